// Round 6
// baseline (3760.493 us; speedup 1.0000x reference)
//
#include <hip/hip_runtime.h>

#define H 128
#define FN 16
#define FE 8
#define NBUK_MAX 1600   // buckets = ceil(N/64) = 1563 for N=100k

// ============================ histogram (both sorts fused) ============================
__global__ __launch_bounds__(256) void k_hist2(
    const int* __restrict__ k1, const int* __restrict__ k2,
    int* __restrict__ bcnt1, int* __restrict__ bcnt2, int E, int nbuk) {
  __shared__ int h1[NBUK_MAX], h2[NBUK_MAX];
  for (int i = threadIdx.x; i < nbuk; i += 256) { h1[i] = 0; h2[i] = 0; }
  __syncthreads();
  for (int e = blockIdx.x * 256 + threadIdx.x; e < E; e += gridDim.x * 256) {
    atomicAdd(&h1[k1[e] >> 6], 1);
    atomicAdd(&h2[k2[e] >> 6], 1);
  }
  __syncthreads();
  for (int i = threadIdx.x; i < nbuk; i += 256) {
    if (h1[i]) atomicAdd(&bcnt1[i], h1[i]);
    if (h2[i]) atomicAdd(&bcnt2[i], h2[i]);
  }
}

// ============================ single-block dual scan ============================
__global__ __launch_bounds__(1024) void k_scan(
    const int* __restrict__ cnt1, int* __restrict__ st1, int* __restrict__ gc1,
    const int* __restrict__ cnt2, int* __restrict__ st2, int* __restrict__ gc2,
    int nbuk) {
  __shared__ int s[1024];
  int tid = threadIdx.x;
  for (int pass = 0; pass < 2; pass++) {
    const int* cnt = pass ? cnt2 : cnt1;
    int* st = pass ? st2 : st1;
    int* gc = pass ? gc2 : gc1;
    int run = 0;
    for (int half = 0; half * 1024 < nbuk; half++) {
      int i = half * 1024 + tid;
      int v = (i < nbuk) ? cnt[i] : 0;
      s[tid] = v; __syncthreads();
      for (int off = 1; off < 1024; off <<= 1) {
        int t = (tid >= off) ? s[tid - off] : 0;
        __syncthreads();
        s[tid] += t;
        __syncthreads();
      }
      int excl = run + s[tid] - v;
      if (i < nbuk) { st[i] = excl; gc[i] = excl; }
      run += s[1023];
      __syncthreads();
    }
    if (tid == 0) st[nbuk] = run;
    __syncthreads();
  }
}

// ============================ pass-1 bucket scatter ============================
template <int PACKED>
__global__ __launch_bounds__(256) void k_p1_scatter(
    const int* __restrict__ key, const int* __restrict__ dsts,
    const float* __restrict__ vals, int* __restrict__ gcur,
    int* __restrict__ pkey, int2* __restrict__ bpay, int E, int nbuk) {
  __shared__ int hc[NBUK_MAX];
  int tid = threadIdx.x;
  int c0 = blockIdx.x * 8192;
  int c1 = min(c0 + 8192, E);
  for (int i = tid; i < nbuk; i += 256) hc[i] = 0;
  __syncthreads();
  for (int e = c0 + tid; e < c1; e += 256)
    atomicAdd(&hc[key[e] >> 6], 1);
  __syncthreads();
  for (int i = tid; i < nbuk; i += 256) {
    int c = hc[i];
    if (c) hc[i] = atomicAdd(&gcur[i], c);
  }
  __syncthreads();
  for (int e = c0 + tid; e < c1; e += 256) {
    int k = key[e];
    int pos = atomicAdd(&hc[k >> 6], 1);
    if (PACKED) {
      pkey[pos] = (e << 6) | (k & 63);
    } else {
      bpay[pos] = make_int2(dsts[e] | ((k & 63) << 20), __float_as_int(vals[e]));
    }
  }
}

// ============================ embed bucket-sum ============================
__global__ __launch_bounds__(256) void k_embed_agg(
    const int* __restrict__ pkey, const float* __restrict__ edge_attr,
    const int* __restrict__ bstart, float* __restrict__ agg8, int N) {
  __shared__ float lds[FE][64];
  int b = blockIdx.x, tid = threadIdx.x;
  for (int i = tid; i < FE * 64; i += 256) ((float*)lds)[i] = 0.f;
  __syncthreads();
  int s = bstart[b], t = bstart[b + 1];
  for (int i = s + tid; i < t; i += 256) {
    int pk = pkey[i];
    int e = pk >> 6, slot = pk & 63;
    const float4* ea = (const float4*)(edge_attr + (size_t)e * FE);
    float4 a = ea[0], b4 = ea[1];
    atomicAdd(&lds[0][slot], a.x);  atomicAdd(&lds[1][slot], a.y);
    atomicAdd(&lds[2][slot], a.z);  atomicAdd(&lds[3][slot], a.w);
    atomicAdd(&lds[4][slot], b4.x); atomicAdd(&lds[5][slot], b4.y);
    atomicAdd(&lds[6][slot], b4.z); atomicAdd(&lds[7][slot], b4.w);
  }
  __syncthreads();
  int node0 = b * 64;
  for (int i = tid; i < 64 * FE; i += 256) {
    int n = node0 + (i >> 3);
    if (n < N) agg8[(size_t)n * FE + (i & 7)] = lds[i & 7][i >> 3];
  }
}

// ============================ pass-2 for adj sort ============================
__global__ __launch_bounds__(256) void k_p2(
    const int2* __restrict__ bpay, const int* __restrict__ bstart,
    int* __restrict__ offs, int2* __restrict__ payF, int N, int E) {
  __shared__ int cnt[64], scn[64], cur[64];
  int b = blockIdx.x, tid = threadIdx.x;
  int s = bstart[b], t = bstart[b + 1];
  if (tid < 64) cnt[tid] = 0;
  __syncthreads();
  for (int i = s + tid; i < t; i += 256) atomicAdd(&cnt[(bpay[i].x >> 20) & 63], 1);
  __syncthreads();
  if (tid < 64) scn[tid] = cnt[tid];
  __syncthreads();
  for (int off = 1; off < 64; off <<= 1) {
    int v = 0;
    if (tid < 64 && tid >= off) v = scn[tid - off];
    __syncthreads();
    if (tid < 64 && tid >= off) scn[tid] += v;
    __syncthreads();
  }
  if (tid < 64) {
    int excl = s + scn[tid] - cnt[tid];
    cur[tid] = excl;
    int node = b * 64 + tid;
    if (node < N) offs[node] = excl;
  }
  if (b == 0 && tid == 0) offs[N] = E;
  __syncthreads();
  for (int i = s + tid; i < t; i += 256) {
    int2 p = bpay[i];
    int slot = (p.x >> 20) & 63;
    int pos = atomicAdd(&cur[slot], 1);
    payF[pos] = make_int2(p.x & 0xFFFFF, p.y);
  }
}

// ============================ embed h ============================
__global__ __launch_bounds__(256) void k_embed_h(
    const float* __restrict__ node_attr, const float* __restrict__ Wn,
    const float* __restrict__ We8, const float* __restrict__ b,
    const float* __restrict__ agg8, float* __restrict__ h, int N) {
  __shared__ float Ws[FN * H];
  __shared__ float Es[FE * H];
  __shared__ float na[2][FN];
  __shared__ float a8[2][FE];
  for (int i = threadIdx.x; i < FN * H; i += 256) Ws[i] = Wn[i];
  for (int i = threadIdx.x; i < FE * H; i += 256) Es[i] = We8[i];
  int lane = threadIdx.x & 127;
  int sub  = threadIdx.x >> 7;
  for (int n0 = blockIdx.x * 2; n0 < N; n0 += gridDim.x * 2) {
    int n = n0 + sub;
    __syncthreads();
    if (n < N) {
      if (lane < FN) na[sub][lane] = node_attr[(size_t)n * FN + lane];
      else if (lane < FN + FE) a8[sub][lane - FN] = agg8[(size_t)n * FE + (lane - FN)];
    }
    __syncthreads();
    if (n < N) {
      float acc = b[lane];
#pragma unroll
      for (int k = 0; k < FN; k++) acc += na[sub][k] * Ws[k * H + lane];
#pragma unroll
      for (int k = 0; k < FE; k++) acc += a8[sub][k] * Es[k * H + lane];
      h[(size_t)n * H + lane] = fmaxf(acc, 0.f);
    }
  }
}

// ============================ LDS GEMM [N,128]@[128,128]+b ============================
// 128x128 tile, 256 threads, 8 rows x 8 cols per thread (acc 64 VGPR).
// K in 4 chunks of 32, register-prefetch of next chunk during compute.
// hs padded (stride 9 float4) and cols split c/c+16 -> conflict-free LDS.
template <int RELU_OUT>
__global__ __launch_bounds__(256, 3) void k_gemm(
    const float* __restrict__ in, const float* __restrict__ W,
    const float* __restrict__ bias, float* __restrict__ out, int N) {
  __shared__ float4 Ws4[32 * 32];    // [k(0..31)][col4(0..31)]  16 KB
  __shared__ float4 hs4[128 * 9];    // [row][k4(0..7)] pad->9   18 KB
  int tid = threadIdx.x;
  int c  = tid & 15;                 // col4 c and c+16
  int rg = tid >> 4;                 // rows rg + 16*i
  int rowBase = blockIdx.x * 128;
  const float4* in4 = (const float4*)in;   // [N][32]
  const float4* Wg4 = (const float4*)W;    // [128][32]

  float4 acc[8][2];
#pragma unroll
  for (int i = 0; i < 8; i++) {
    acc[i][0] = make_float4(0.f, 0.f, 0.f, 0.f);
    acc[i][1] = make_float4(0.f, 0.f, 0.f, 0.f);
  }

  // staging row indices (clamped for safe loads; stores guarded)
  int srow[4], skq[4];
#pragma unroll
  for (int j = 0; j < 4; j++) {
    int q = tid + 256 * j;
    int r = rowBase + (q >> 3);
    srow[j] = (r < N) ? r : (N - 1);
    skq[j] = q & 7;
  }

  float4 wpre[4], hpre[4];
#pragma unroll
  for (int j = 0; j < 4; j++) {
    wpre[j] = Wg4[tid + 256 * j];                       // chunk 0
    hpre[j] = in4[(size_t)srow[j] * 32 + skq[j]];       // chunk 0 (kk*8 = 0)
  }

  for (int kk = 0; kk < 4; kk++) {
    if (kk) __syncthreads();            // prev compute done reading LDS
#pragma unroll
    for (int j = 0; j < 4; j++) {
      int q = tid + 256 * j;
      Ws4[q] = wpre[j];
      hs4[(q >> 3) * 9 + (q & 7)] = hpre[j];
    }
    __syncthreads();
    if (kk < 3) {
#pragma unroll
      for (int j = 0; j < 4; j++) {
        wpre[j] = Wg4[(kk + 1) * 1024 + tid + 256 * j];
        hpre[j] = in4[(size_t)srow[j] * 32 + (kk + 1) * 8 + skq[j]];
      }
    }
#pragma unroll
    for (int k4 = 0; k4 < 8; k4++) {
      float4 wa[4], wb[4];
#pragma unroll
      for (int j = 0; j < 4; j++) {
        wa[j] = Ws4[(k4 * 4 + j) * 32 + c];
        wb[j] = Ws4[(k4 * 4 + j) * 32 + 16 + c];
      }
#pragma unroll
      for (int i = 0; i < 8; i++) {
        float4 hv = hs4[(rg + 16 * i) * 9 + k4];
        acc[i][0].x += hv.x * wa[0].x + hv.y * wa[1].x + hv.z * wa[2].x + hv.w * wa[3].x;
        acc[i][0].y += hv.x * wa[0].y + hv.y * wa[1].y + hv.z * wa[2].y + hv.w * wa[3].y;
        acc[i][0].z += hv.x * wa[0].z + hv.y * wa[1].z + hv.z * wa[2].z + hv.w * wa[3].z;
        acc[i][0].w += hv.x * wa[0].w + hv.y * wa[1].w + hv.z * wa[2].w + hv.w * wa[3].w;
        acc[i][1].x += hv.x * wb[0].x + hv.y * wb[1].x + hv.z * wb[2].x + hv.w * wb[3].x;
        acc[i][1].y += hv.x * wb[0].y + hv.y * wb[1].y + hv.z * wb[2].y + hv.w * wb[3].y;
        acc[i][1].z += hv.x * wb[0].z + hv.y * wb[1].z + hv.z * wb[2].z + hv.w * wb[3].z;
        acc[i][1].w += hv.x * wb[0].w + hv.y * wb[1].w + hv.z * wb[2].w + hv.w * wb[3].w;
      }
    }
  }

  float4 bva = ((const float4*)bias)[c];
  float4 bvb = ((const float4*)bias)[16 + c];
#pragma unroll
  for (int i = 0; i < 8; i++) {
    int row = rowBase + rg + 16 * i;
    if (row < N) {
      float4 oa = make_float4(acc[i][0].x + bva.x, acc[i][0].y + bva.y,
                              acc[i][0].z + bva.z, acc[i][0].w + bva.w);
      float4 ob = make_float4(acc[i][1].x + bvb.x, acc[i][1].y + bvb.y,
                              acc[i][1].z + bvb.z, acc[i][1].w + bvb.w);
      if (RELU_OUT) {
        oa.x = fmaxf(oa.x, 0.f); oa.y = fmaxf(oa.y, 0.f);
        oa.z = fmaxf(oa.z, 0.f); oa.w = fmaxf(oa.w, 0.f);
        ob.x = fmaxf(ob.x, 0.f); ob.y = fmaxf(ob.y, 0.f);
        ob.z = fmaxf(ob.z, 0.f); ob.w = fmaxf(ob.w, 0.f);
      }
      ((float4*)out)[(size_t)row * 32 + c] = oa;
      ((float4*)out)[(size_t)row * 32 + 16 + c] = ob;
    }
  }
}

// ============================ GCN gather-aggregate ============================
__global__ __launch_bounds__(256) void k_gcn_gather(
    const float* __restrict__ hw, const int* __restrict__ offs,
    const int2* __restrict__ pay, float* __restrict__ out, int N) {
  int n = blockIdx.x * 8 + (threadIdx.x >> 5);
  if (n >= N) return;
  int c = threadIdx.x & 31;
  int s = offs[n], t = offs[n + 1];
  float4 acc = make_float4(0.f, 0.f, 0.f, 0.f);
  for (int i = s; i < t; i++) {
    int2 p = pay[i];
    float v = __int_as_float(p.y);
    float4 hv = ((const float4*)hw)[(size_t)p.x * 32 + c];
    acc.x += v * hv.x; acc.y += v * hv.y;
    acc.z += v * hv.z; acc.w += v * hv.w;
  }
  float4 o = make_float4(fmaxf(acc.x, 0.f), fmaxf(acc.y, 0.f),
                         fmaxf(acc.z, 0.f), fmaxf(acc.w, 0.f));
  ((float4*)(out + (size_t)n * H))[c] = o;
}

// ============================ pool + predictor ============================
__global__ __launch_bounds__(256) void k_gbounds(
    const int* __restrict__ batch, int* __restrict__ gstart, int N, int G) {
  int n = blockIdx.x * 256 + threadIdx.x;
  if (n > N) return;
  if (n == 0) {
    for (int g = 0; g <= batch[0]; g++) gstart[g] = 0;
  } else if (n == N) {
    for (int g = batch[N - 1] + 1; g <= G; g++) gstart[g] = N;
  } else {
    int b0 = batch[n - 1], b1 = batch[n];
    for (int g = b0 + 1; g <= b1; g++) gstart[g] = n;
  }
}

__global__ __launch_bounds__(128) void k_pool_seg(
    const float* __restrict__ h, const int* __restrict__ gstart,
    float* __restrict__ fp, int G) {
  int g = blockIdx.x;
  int j = threadIdx.x;
  int s = gstart[g], t = gstart[g + 1];
  float acc = 0.f;
  for (int n = s; n < t; n++) acc += h[(size_t)n * H + j];
  fp[(size_t)g * H + j] = acc;
}

__global__ __launch_bounds__(256) void k_pred2(
    const float* __restrict__ z, const float* __restrict__ Wp2,
    const float* __restrict__ bp2, float* __restrict__ out, int G) {
  int g = blockIdx.x * 4 + (threadIdx.x >> 6);
  if (g >= G) return;
  int l = threadIdx.x & 63;
  float2 zv = ((const float2*)z)[(size_t)g * 64 + l];
  float2 wv = ((const float2*)Wp2)[l];
  float v = zv.x * wv.x + zv.y * wv.y;
#pragma unroll
  for (int off = 32; off > 0; off >>= 1) v += __shfl_down(v, off, 64);
  if (l == 0) out[g] = v + bp2[0];
}

// ============================ launch ============================
extern "C" void kernel_launch(void* const* d_in, const int* in_sizes, int n_in,
                              void* d_out, int out_size, void* d_ws, size_t ws_size,
                              hipStream_t stream) {
  const float* node_attr  = (const float*)d_in[0];
  const float* edge_attr  = (const float*)d_in[1];
  const int*   edge_index = (const int*)d_in[2];
  const int*   adj_index  = (const int*)d_in[3];
  const float* adj_value  = (const float*)d_in[4];
  const int*   batch      = (const int*)d_in[5];
  const float* W_node  = (const float*)d_in[6];
  const float* W_edge  = (const float*)d_in[7];
  const float* b_embed = (const float*)d_in[8];
  const float* W1 = (const float*)d_in[9];
  const float* b1 = (const float*)d_in[10];
  const float* W2 = (const float*)d_in[11];
  const float* b2 = (const float*)d_in[12];
  const float* W3 = (const float*)d_in[13];
  const float* b3 = (const float*)d_in[14];
  const float* Wp1 = (const float*)d_in[15];
  const float* bp1 = (const float*)d_in[16];
  const float* Wp2 = (const float*)d_in[17];
  const float* bp2 = (const float*)d_in[18];
  float* out = (float*)d_out;

  const int E = in_sizes[4];           // 1,600,000
  const int N = in_sizes[5];           // 100,000
  const int G = out_size;              // 2048
  const int nbuk = (N + 63) >> 6;      // 1563
  const int p1b = (E + 8191) / 8192;

  // ---- workspace layout ----
  float* A     = (float*)d_ws;                       // N*H
  float* B     = A + (size_t)N * H;                  // N*H
  int2*  payF  = (int2*)(B + (size_t)N * H);         // E
  float* fpool = (float*)(payF + E);                 // G*H
  int*   bcnt1 = (int*)(fpool + (size_t)G * H);      // nbuk  } one memset
  int*   bcnt2 = bcnt1 + nbuk;                       // nbuk  }
  int*   bst1  = bcnt2 + nbuk;                       // nbuk+1
  int*   gcur1 = bst1 + nbuk + 1;                    // nbuk
  int*   bst2  = gcur1 + nbuk;                       // nbuk+1
  int*   gcur2 = bst2 + nbuk + 1;                    // nbuk
  int*   offs2 = gcur2 + nbuk;                       // N+1
  int*   gstart= offs2 + N + 1;                      // G+1
  // transient aliases (lifetimes by launch order):
  float* agg8  = A;                                  // N*FE; dead after embed_h
  int*   pkey  = (int*)B;                            // E ints; dead after embed_agg
  int2*  bpay2 = (int2*)(((int*)B) + E);             // E int2; dead after p2
  float* zbuf  = A;                                  // G*H; A free after last gather

  // ---- histograms + scans (both sorts) ----
  hipMemsetAsync(bcnt1, 0, (size_t)2 * nbuk * sizeof(int), stream);
  k_hist2<<<512, 256, 0, stream>>>(edge_index + E, adj_index, bcnt1, bcnt2, E, nbuk);
  k_scan<<<1, 1024, 0, stream>>>(bcnt1, bst1, gcur1, bcnt2, bst2, gcur2, nbuk);

  // ---- pass-1 scatters ----
  k_p1_scatter<1><<<p1b, 256, 0, stream>>>(edge_index + E, nullptr, nullptr,
                                           gcur1, pkey, nullptr, E, nbuk);
  k_p1_scatter<0><<<p1b, 256, 0, stream>>>(adj_index, adj_index + E, adj_value,
                                           gcur2, nullptr, bpay2, E, nbuk);

  // ---- embed agg + adj pass-2 ----
  k_embed_agg<<<nbuk, 256, 0, stream>>>(pkey, edge_attr, bst1, agg8, N);
  k_p2<<<nbuk, 256, 0, stream>>>(bpay2, bst2, offs2, payF, N, E);

  // ---- embed h -> B ----
  k_embed_h<<<4096, 256, 0, stream>>>(node_attr, W_node, W_edge, b_embed, agg8, B, N);

  k_gbounds<<<(N + 256) / 256, 256, 0, stream>>>(batch, gstart, N, G);

  // ---- 3 GCN layers: A = B@W+b ; B = relu(gather(A)) ----
  int gemm_blocks = (N + 127) / 128;
  int agb = (N + 7) / 8;
  k_gemm<0><<<gemm_blocks, 256, 0, stream>>>(B, W1, b1, A, N);
  k_gcn_gather<<<agb, 256, 0, stream>>>(A, offs2, payF, B, N);
  k_gemm<0><<<gemm_blocks, 256, 0, stream>>>(B, W2, b2, A, N);
  k_gcn_gather<<<agb, 256, 0, stream>>>(A, offs2, payF, B, N);
  k_gemm<0><<<gemm_blocks, 256, 0, stream>>>(B, W3, b3, A, N);
  k_gcn_gather<<<agb, 256, 0, stream>>>(A, offs2, payF, B, N);

  // ---- pool + predictor ----
  k_pool_seg<<<G, 128, 0, stream>>>(B, gstart, fpool, G);
  k_gemm<1><<<G / 128, 256, 0, stream>>>(fpool, Wp1, bp1, zbuf, G);
  k_pred2<<<(G + 3) / 4, 256, 0, stream>>>(zbuf, Wp2, bp2, out, G);
}

// Round 7
// 1528.213 us; speedup vs baseline: 2.4607x; 2.4607x over previous
//
#include <hip/hip_runtime.h>

#define H 128
#define FN 16
#define FE 8
#define NBUK_MAX 1600   // buckets = ceil(N/64) = 1563 for N=100k

// ============================ histogram (both sorts fused) ============================
__global__ __launch_bounds__(256) void k_hist2(
    const int* __restrict__ k1, const int* __restrict__ k2,
    int* __restrict__ bcnt1, int* __restrict__ bcnt2, int E, int nbuk) {
  __shared__ int h1[NBUK_MAX], h2[NBUK_MAX];
  for (int i = threadIdx.x; i < nbuk; i += 256) { h1[i] = 0; h2[i] = 0; }
  __syncthreads();
  for (int e = blockIdx.x * 256 + threadIdx.x; e < E; e += gridDim.x * 256) {
    atomicAdd(&h1[k1[e] >> 6], 1);
    atomicAdd(&h2[k2[e] >> 6], 1);
  }
  __syncthreads();
  for (int i = threadIdx.x; i < nbuk; i += 256) {
    if (h1[i]) atomicAdd(&bcnt1[i], h1[i]);
    if (h2[i]) atomicAdd(&bcnt2[i], h2[i]);
  }
}

// ============================ single-block dual scan ============================
__global__ __launch_bounds__(1024) void k_scan(
    const int* __restrict__ cnt1, int* __restrict__ st1, int* __restrict__ gc1,
    const int* __restrict__ cnt2, int* __restrict__ st2, int* __restrict__ gc2,
    int nbuk) {
  __shared__ int s[1024];
  int tid = threadIdx.x;
  for (int pass = 0; pass < 2; pass++) {
    const int* cnt = pass ? cnt2 : cnt1;
    int* st = pass ? st2 : st1;
    int* gc = pass ? gc2 : gc1;
    int run = 0;
    for (int half = 0; half * 1024 < nbuk; half++) {
      int i = half * 1024 + tid;
      int v = (i < nbuk) ? cnt[i] : 0;
      s[tid] = v; __syncthreads();
      for (int off = 1; off < 1024; off <<= 1) {
        int t = (tid >= off) ? s[tid - off] : 0;
        __syncthreads();
        s[tid] += t;
        __syncthreads();
      }
      int excl = run + s[tid] - v;
      if (i < nbuk) { st[i] = excl; gc[i] = excl; }
      run += s[1023];
      __syncthreads();
    }
    if (tid == 0) st[nbuk] = run;
    __syncthreads();
  }
}

// ============================ pass-1 bucket scatter ============================
template <int PACKED>
__global__ __launch_bounds__(256) void k_p1_scatter(
    const int* __restrict__ key, const int* __restrict__ dsts,
    const float* __restrict__ vals, int* __restrict__ gcur,
    int* __restrict__ pkey, int2* __restrict__ bpay, int E, int nbuk) {
  __shared__ int hc[NBUK_MAX];
  int tid = threadIdx.x;
  int c0 = blockIdx.x * 8192;
  int c1 = min(c0 + 8192, E);
  for (int i = tid; i < nbuk; i += 256) hc[i] = 0;
  __syncthreads();
  for (int e = c0 + tid; e < c1; e += 256)
    atomicAdd(&hc[key[e] >> 6], 1);
  __syncthreads();
  for (int i = tid; i < nbuk; i += 256) {
    int c = hc[i];
    if (c) hc[i] = atomicAdd(&gcur[i], c);
  }
  __syncthreads();
  for (int e = c0 + tid; e < c1; e += 256) {
    int k = key[e];
    int pos = atomicAdd(&hc[k >> 6], 1);
    if (PACKED) {
      pkey[pos] = (e << 6) | (k & 63);
    } else {
      bpay[pos] = make_int2(dsts[e] | ((k & 63) << 20), __float_as_int(vals[e]));
    }
  }
}

// ============================ embed bucket-sum ============================
__global__ __launch_bounds__(256) void k_embed_agg(
    const int* __restrict__ pkey, const float* __restrict__ edge_attr,
    const int* __restrict__ bstart, float* __restrict__ agg8, int N) {
  __shared__ float lds[FE][64];
  int b = blockIdx.x, tid = threadIdx.x;
  for (int i = tid; i < FE * 64; i += 256) ((float*)lds)[i] = 0.f;
  __syncthreads();
  int s = bstart[b], t = bstart[b + 1];
  for (int i = s + tid; i < t; i += 256) {
    int pk = pkey[i];
    int e = pk >> 6, slot = pk & 63;
    const float4* ea = (const float4*)(edge_attr + (size_t)e * FE);
    float4 a = ea[0], b4 = ea[1];
    atomicAdd(&lds[0][slot], a.x);  atomicAdd(&lds[1][slot], a.y);
    atomicAdd(&lds[2][slot], a.z);  atomicAdd(&lds[3][slot], a.w);
    atomicAdd(&lds[4][slot], b4.x); atomicAdd(&lds[5][slot], b4.y);
    atomicAdd(&lds[6][slot], b4.z); atomicAdd(&lds[7][slot], b4.w);
  }
  __syncthreads();
  int node0 = b * 64;
  for (int i = tid; i < 64 * FE; i += 256) {
    int n = node0 + (i >> 3);
    if (n < N) agg8[(size_t)n * FE + (i & 7)] = lds[i & 7][i >> 3];
  }
}

// ============================ pass-2 for adj sort ============================
__global__ __launch_bounds__(256) void k_p2(
    const int2* __restrict__ bpay, const int* __restrict__ bstart,
    int* __restrict__ offs, int2* __restrict__ payF, int N, int E) {
  __shared__ int cnt[64], scn[64], cur[64];
  int b = blockIdx.x, tid = threadIdx.x;
  int s = bstart[b], t = bstart[b + 1];
  if (tid < 64) cnt[tid] = 0;
  __syncthreads();
  for (int i = s + tid; i < t; i += 256) atomicAdd(&cnt[(bpay[i].x >> 20) & 63], 1);
  __syncthreads();
  if (tid < 64) scn[tid] = cnt[tid];
  __syncthreads();
  for (int off = 1; off < 64; off <<= 1) {
    int v = 0;
    if (tid < 64 && tid >= off) v = scn[tid - off];
    __syncthreads();
    if (tid < 64 && tid >= off) scn[tid] += v;
    __syncthreads();
  }
  if (tid < 64) {
    int excl = s + scn[tid] - cnt[tid];
    cur[tid] = excl;
    int node = b * 64 + tid;
    if (node < N) offs[node] = excl;
  }
  if (b == 0 && tid == 0) offs[N] = E;
  __syncthreads();
  for (int i = s + tid; i < t; i += 256) {
    int2 p = bpay[i];
    int slot = (p.x >> 20) & 63;
    int pos = atomicAdd(&cur[slot], 1);
    payF[pos] = make_int2(p.x & 0xFFFFF, p.y);
  }
}

// ============================ embed h ============================
__global__ __launch_bounds__(256) void k_embed_h(
    const float* __restrict__ node_attr, const float* __restrict__ Wn,
    const float* __restrict__ We8, const float* __restrict__ b,
    const float* __restrict__ agg8, float* __restrict__ h, int N) {
  __shared__ float Ws[FN * H];
  __shared__ float Es[FE * H];
  __shared__ float na[2][FN];
  __shared__ float a8[2][FE];
  for (int i = threadIdx.x; i < FN * H; i += 256) Ws[i] = Wn[i];
  for (int i = threadIdx.x; i < FE * H; i += 256) Es[i] = We8[i];
  int lane = threadIdx.x & 127;
  int sub  = threadIdx.x >> 7;
  for (int n0 = blockIdx.x * 2; n0 < N; n0 += gridDim.x * 2) {
    int n = n0 + sub;
    __syncthreads();
    if (n < N) {
      if (lane < FN) na[sub][lane] = node_attr[(size_t)n * FN + lane];
      else if (lane < FN + FE) a8[sub][lane - FN] = agg8[(size_t)n * FE + (lane - FN)];
    }
    __syncthreads();
    if (n < N) {
      float acc = b[lane];
#pragma unroll
      for (int k = 0; k < FN; k++) acc += na[sub][k] * Ws[k * H + lane];
#pragma unroll
      for (int k = 0; k < FE; k++) acc += a8[sub][k] * Es[k * H + lane];
      h[(size_t)n * H + lane] = fmaxf(acc, 0.f);
    }
  }
}

// ============================ LDS GEMM [N,128]@[128,128]+b ============================
// 128x128 tile, 256 threads, 8 rows x 8 cols per thread (acc 64 VGPR).
// K in 4 chunks of 32, register-prefetch of next chunk during compute.
// NOTE: no min-occupancy arg in launch_bounds — round 6's (256,3) capped the
// allocator at ~85 VGPRs and spilled the 64-reg accumulator to scratch
// (2.1 GB HBM traffic, 892 us). Free allocation -> ~130-160 VGPR, no spill.
template <int RELU_OUT>
__global__ __launch_bounds__(256) void k_gemm(
    const float* __restrict__ in, const float* __restrict__ W,
    const float* __restrict__ bias, float* __restrict__ out, int N) {
  __shared__ float4 Ws4[32 * 32];    // [k(0..31)][col4(0..31)]  16 KB
  __shared__ float4 hs4[128 * 9];    // [row][k4(0..7)] pad->9   18 KB
  int tid = threadIdx.x;
  int c  = tid & 15;                 // col4 c and c+16
  int rg = tid >> 4;                 // rows rg + 16*i
  int rowBase = blockIdx.x * 128;
  const float4* in4 = (const float4*)in;   // [N][32]
  const float4* Wg4 = (const float4*)W;    // [128][32]

  float4 acc[8][2];
#pragma unroll
  for (int i = 0; i < 8; i++) {
    acc[i][0] = make_float4(0.f, 0.f, 0.f, 0.f);
    acc[i][1] = make_float4(0.f, 0.f, 0.f, 0.f);
  }

  // staging row indices (clamped for safe loads; stores guarded)
  int srow[4], skq[4];
#pragma unroll
  for (int j = 0; j < 4; j++) {
    int q = tid + 256 * j;
    int r = rowBase + (q >> 3);
    srow[j] = (r < N) ? r : (N - 1);
    skq[j] = q & 7;
  }

  float4 wpre[4], hpre[4];
#pragma unroll
  for (int j = 0; j < 4; j++) {
    wpre[j] = Wg4[tid + 256 * j];                       // chunk 0
    hpre[j] = in4[(size_t)srow[j] * 32 + skq[j]];       // chunk 0 (kk*8 = 0)
  }

  for (int kk = 0; kk < 4; kk++) {
    if (kk) __syncthreads();            // prev compute done reading LDS
#pragma unroll
    for (int j = 0; j < 4; j++) {
      int q = tid + 256 * j;
      Ws4[q] = wpre[j];
      hs4[(q >> 3) * 9 + (q & 7)] = hpre[j];
    }
    __syncthreads();
    if (kk < 3) {
#pragma unroll
      for (int j = 0; j < 4; j++) {
        wpre[j] = Wg4[(kk + 1) * 1024 + tid + 256 * j];
        hpre[j] = in4[(size_t)srow[j] * 32 + (kk + 1) * 8 + skq[j]];
      }
    }
#pragma unroll
    for (int k4 = 0; k4 < 8; k4++) {
      float4 wa[4], wb[4];
#pragma unroll
      for (int j = 0; j < 4; j++) {
        wa[j] = Ws4[(k4 * 4 + j) * 32 + c];
        wb[j] = Ws4[(k4 * 4 + j) * 32 + 16 + c];
      }
#pragma unroll
      for (int i = 0; i < 8; i++) {
        float4 hv = hs4[(rg + 16 * i) * 9 + k4];
        acc[i][0].x += hv.x * wa[0].x + hv.y * wa[1].x + hv.z * wa[2].x + hv.w * wa[3].x;
        acc[i][0].y += hv.x * wa[0].y + hv.y * wa[1].y + hv.z * wa[2].y + hv.w * wa[3].y;
        acc[i][0].z += hv.x * wa[0].z + hv.y * wa[1].z + hv.z * wa[2].z + hv.w * wa[3].z;
        acc[i][0].w += hv.x * wa[0].w + hv.y * wa[1].w + hv.z * wa[2].w + hv.w * wa[3].w;
        acc[i][1].x += hv.x * wb[0].x + hv.y * wb[1].x + hv.z * wb[2].x + hv.w * wb[3].x;
        acc[i][1].y += hv.x * wb[0].y + hv.y * wb[1].y + hv.z * wb[2].y + hv.w * wb[3].y;
        acc[i][1].z += hv.x * wb[0].z + hv.y * wb[1].z + hv.z * wb[2].z + hv.w * wb[3].z;
        acc[i][1].w += hv.x * wb[0].w + hv.y * wb[1].w + hv.z * wb[2].w + hv.w * wb[3].w;
      }
    }
  }

  float4 bva = ((const float4*)bias)[c];
  float4 bvb = ((const float4*)bias)[16 + c];
#pragma unroll
  for (int i = 0; i < 8; i++) {
    int row = rowBase + rg + 16 * i;
    if (row < N) {
      float4 oa = make_float4(acc[i][0].x + bva.x, acc[i][0].y + bva.y,
                              acc[i][0].z + bva.z, acc[i][0].w + bva.w);
      float4 ob = make_float4(acc[i][1].x + bvb.x, acc[i][1].y + bvb.y,
                              acc[i][1].z + bvb.z, acc[i][1].w + bvb.w);
      if (RELU_OUT) {
        oa.x = fmaxf(oa.x, 0.f); oa.y = fmaxf(oa.y, 0.f);
        oa.z = fmaxf(oa.z, 0.f); oa.w = fmaxf(oa.w, 0.f);
        ob.x = fmaxf(ob.x, 0.f); ob.y = fmaxf(ob.y, 0.f);
        ob.z = fmaxf(ob.z, 0.f); ob.w = fmaxf(ob.w, 0.f);
      }
      ((float4*)out)[(size_t)row * 32 + c] = oa;
      ((float4*)out)[(size_t)row * 32 + 16 + c] = ob;
    }
  }
}

// ============================ GCN gather-aggregate ============================
__global__ __launch_bounds__(256) void k_gcn_gather(
    const float* __restrict__ hw, const int* __restrict__ offs,
    const int2* __restrict__ pay, float* __restrict__ out, int N) {
  int n = blockIdx.x * 8 + (threadIdx.x >> 5);
  if (n >= N) return;
  int c = threadIdx.x & 31;
  int s = offs[n], t = offs[n + 1];
  float4 acc = make_float4(0.f, 0.f, 0.f, 0.f);
  for (int i = s; i < t; i++) {
    int2 p = pay[i];
    float v = __int_as_float(p.y);
    float4 hv = ((const float4*)hw)[(size_t)p.x * 32 + c];
    acc.x += v * hv.x; acc.y += v * hv.y;
    acc.z += v * hv.z; acc.w += v * hv.w;
  }
  float4 o = make_float4(fmaxf(acc.x, 0.f), fmaxf(acc.y, 0.f),
                         fmaxf(acc.z, 0.f), fmaxf(acc.w, 0.f));
  ((float4*)(out + (size_t)n * H))[c] = o;
}

// ============================ pool + predictor ============================
__global__ __launch_bounds__(256) void k_gbounds(
    const int* __restrict__ batch, int* __restrict__ gstart, int N, int G) {
  int n = blockIdx.x * 256 + threadIdx.x;
  if (n > N) return;
  if (n == 0) {
    for (int g = 0; g <= batch[0]; g++) gstart[g] = 0;
  } else if (n == N) {
    for (int g = batch[N - 1] + 1; g <= G; g++) gstart[g] = N;
  } else {
    int b0 = batch[n - 1], b1 = batch[n];
    for (int g = b0 + 1; g <= b1; g++) gstart[g] = n;
  }
}

__global__ __launch_bounds__(128) void k_pool_seg(
    const float* __restrict__ h, const int* __restrict__ gstart,
    float* __restrict__ fp, int G) {
  int g = blockIdx.x;
  int j = threadIdx.x;
  int s = gstart[g], t = gstart[g + 1];
  float acc = 0.f;
  for (int n = s; n < t; n++) acc += h[(size_t)n * H + j];
  fp[(size_t)g * H + j] = acc;
}

__global__ __launch_bounds__(256) void k_pred2(
    const float* __restrict__ z, const float* __restrict__ Wp2,
    const float* __restrict__ bp2, float* __restrict__ out, int G) {
  int g = blockIdx.x * 4 + (threadIdx.x >> 6);
  if (g >= G) return;
  int l = threadIdx.x & 63;
  float2 zv = ((const float2*)z)[(size_t)g * 64 + l];
  float2 wv = ((const float2*)Wp2)[l];
  float v = zv.x * wv.x + zv.y * wv.y;
#pragma unroll
  for (int off = 32; off > 0; off >>= 1) v += __shfl_down(v, off, 64);
  if (l == 0) out[g] = v + bp2[0];
}

// ============================ launch ============================
extern "C" void kernel_launch(void* const* d_in, const int* in_sizes, int n_in,
                              void* d_out, int out_size, void* d_ws, size_t ws_size,
                              hipStream_t stream) {
  const float* node_attr  = (const float*)d_in[0];
  const float* edge_attr  = (const float*)d_in[1];
  const int*   edge_index = (const int*)d_in[2];
  const int*   adj_index  = (const int*)d_in[3];
  const float* adj_value  = (const float*)d_in[4];
  const int*   batch      = (const int*)d_in[5];
  const float* W_node  = (const float*)d_in[6];
  const float* W_edge  = (const float*)d_in[7];
  const float* b_embed = (const float*)d_in[8];
  const float* W1 = (const float*)d_in[9];
  const float* b1 = (const float*)d_in[10];
  const float* W2 = (const float*)d_in[11];
  const float* b2 = (const float*)d_in[12];
  const float* W3 = (const float*)d_in[13];
  const float* b3 = (const float*)d_in[14];
  const float* Wp1 = (const float*)d_in[15];
  const float* bp1 = (const float*)d_in[16];
  const float* Wp2 = (const float*)d_in[17];
  const float* bp2 = (const float*)d_in[18];
  float* out = (float*)d_out;

  const int E = in_sizes[4];           // 1,600,000
  const int N = in_sizes[5];           // 100,000
  const int G = out_size;              // 2048
  const int nbuk = (N + 63) >> 6;      // 1563
  const int p1b = (E + 8191) / 8192;

  // ---- workspace layout ----
  float* A     = (float*)d_ws;                       // N*H
  float* B     = A + (size_t)N * H;                  // N*H
  int2*  payF  = (int2*)(B + (size_t)N * H);         // E
  float* fpool = (float*)(payF + E);                 // G*H
  int*   bcnt1 = (int*)(fpool + (size_t)G * H);      // nbuk  } one memset
  int*   bcnt2 = bcnt1 + nbuk;                       // nbuk  }
  int*   bst1  = bcnt2 + nbuk;                       // nbuk+1
  int*   gcur1 = bst1 + nbuk + 1;                    // nbuk
  int*   bst2  = gcur1 + nbuk;                       // nbuk+1
  int*   gcur2 = bst2 + nbuk + 1;                    // nbuk
  int*   offs2 = gcur2 + nbuk;                       // N+1
  int*   gstart= offs2 + N + 1;                      // G+1
  // transient aliases (lifetimes by launch order):
  float* agg8  = A;                                  // N*FE; dead after embed_h
  int*   pkey  = (int*)B;                            // E ints; dead after embed_agg
  int2*  bpay2 = (int2*)(((int*)B) + E);             // E int2; dead after p2
  float* zbuf  = A;                                  // G*H; A free after last gather

  // ---- histograms + scans (both sorts) ----
  hipMemsetAsync(bcnt1, 0, (size_t)2 * nbuk * sizeof(int), stream);
  k_hist2<<<512, 256, 0, stream>>>(edge_index + E, adj_index, bcnt1, bcnt2, E, nbuk);
  k_scan<<<1, 1024, 0, stream>>>(bcnt1, bst1, gcur1, bcnt2, bst2, gcur2, nbuk);

  // ---- pass-1 scatters ----
  k_p1_scatter<1><<<p1b, 256, 0, stream>>>(edge_index + E, nullptr, nullptr,
                                           gcur1, pkey, nullptr, E, nbuk);
  k_p1_scatter<0><<<p1b, 256, 0, stream>>>(adj_index, adj_index + E, adj_value,
                                           gcur2, nullptr, bpay2, E, nbuk);

  // ---- embed agg + adj pass-2 ----
  k_embed_agg<<<nbuk, 256, 0, stream>>>(pkey, edge_attr, bst1, agg8, N);
  k_p2<<<nbuk, 256, 0, stream>>>(bpay2, bst2, offs2, payF, N, E);

  // ---- embed h -> B ----
  k_embed_h<<<4096, 256, 0, stream>>>(node_attr, W_node, W_edge, b_embed, agg8, B, N);

  k_gbounds<<<(N + 256) / 256, 256, 0, stream>>>(batch, gstart, N, G);

  // ---- 3 GCN layers: A = B@W+b ; B = relu(gather(A)) ----
  int gemm_blocks = (N + 127) / 128;
  int agb = (N + 7) / 8;
  k_gemm<0><<<gemm_blocks, 256, 0, stream>>>(B, W1, b1, A, N);
  k_gcn_gather<<<agb, 256, 0, stream>>>(A, offs2, payF, B, N);
  k_gemm<0><<<gemm_blocks, 256, 0, stream>>>(B, W2, b2, A, N);
  k_gcn_gather<<<agb, 256, 0, stream>>>(A, offs2, payF, B, N);
  k_gemm<0><<<gemm_blocks, 256, 0, stream>>>(B, W3, b3, A, N);
  k_gcn_gather<<<agb, 256, 0, stream>>>(A, offs2, payF, B, N);

  // ---- pool + predictor ----
  k_pool_seg<<<G, 128, 0, stream>>>(B, gstart, fpool, G);
  k_gemm<1><<<G / 128, 256, 0, stream>>>(fpool, Wp1, bp1, zbuf, G);
  k_pred2<<<(G + 3) / 4, 256, 0, stream>>>(zbuf, Wp2, bp2, out, G);
}

// Round 8
// 1168.113 us; speedup vs baseline: 3.2193x; 1.3083x over previous
//
#include <hip/hip_runtime.h>

#define H 128
#define FN 16
#define FE 8
#define NBUK_MAX 1600   // buckets = ceil(N/64) = 1563 for N=100k

// ============================ histogram (both sorts fused) ============================
__global__ __launch_bounds__(256) void k_hist2(
    const int* __restrict__ k1, const int* __restrict__ k2,
    int* __restrict__ bcnt1, int* __restrict__ bcnt2, int E, int nbuk) {
  __shared__ int h1[NBUK_MAX], h2[NBUK_MAX];
  for (int i = threadIdx.x; i < nbuk; i += 256) { h1[i] = 0; h2[i] = 0; }
  __syncthreads();
  for (int e = blockIdx.x * 256 + threadIdx.x; e < E; e += gridDim.x * 256) {
    atomicAdd(&h1[k1[e] >> 6], 1);
    atomicAdd(&h2[k2[e] >> 6], 1);
  }
  __syncthreads();
  for (int i = threadIdx.x; i < nbuk; i += 256) {
    if (h1[i]) atomicAdd(&bcnt1[i], h1[i]);
    if (h2[i]) atomicAdd(&bcnt2[i], h2[i]);
  }
}

// ============================ single-block dual scan ============================
__global__ __launch_bounds__(1024) void k_scan(
    const int* __restrict__ cnt1, int* __restrict__ st1, int* __restrict__ gc1,
    const int* __restrict__ cnt2, int* __restrict__ st2, int* __restrict__ gc2,
    int nbuk) {
  __shared__ int s[1024];
  int tid = threadIdx.x;
  for (int pass = 0; pass < 2; pass++) {
    const int* cnt = pass ? cnt2 : cnt1;
    int* st = pass ? st2 : st1;
    int* gc = pass ? gc2 : gc1;
    int run = 0;
    for (int half = 0; half * 1024 < nbuk; half++) {
      int i = half * 1024 + tid;
      int v = (i < nbuk) ? cnt[i] : 0;
      s[tid] = v; __syncthreads();
      for (int off = 1; off < 1024; off <<= 1) {
        int t = (tid >= off) ? s[tid - off] : 0;
        __syncthreads();
        s[tid] += t;
        __syncthreads();
      }
      int excl = run + s[tid] - v;
      if (i < nbuk) { st[i] = excl; gc[i] = excl; }
      run += s[1023];
      __syncthreads();
    }
    if (tid == 0) st[nbuk] = run;
    __syncthreads();
  }
}

// ============================ pass-1 bucket scatter ============================
template <int PACKED>
__global__ __launch_bounds__(256) void k_p1_scatter(
    const int* __restrict__ key, const int* __restrict__ dsts,
    const float* __restrict__ vals, int* __restrict__ gcur,
    int* __restrict__ pkey, int2* __restrict__ bpay, int E, int nbuk) {
  __shared__ int hc[NBUK_MAX];
  int tid = threadIdx.x;
  int c0 = blockIdx.x * 8192;
  int c1 = min(c0 + 8192, E);
  for (int i = tid; i < nbuk; i += 256) hc[i] = 0;
  __syncthreads();
  for (int e = c0 + tid; e < c1; e += 256)
    atomicAdd(&hc[key[e] >> 6], 1);
  __syncthreads();
  for (int i = tid; i < nbuk; i += 256) {
    int c = hc[i];
    if (c) hc[i] = atomicAdd(&gcur[i], c);
  }
  __syncthreads();
  for (int e = c0 + tid; e < c1; e += 256) {
    int k = key[e];
    int pos = atomicAdd(&hc[k >> 6], 1);
    if (PACKED) {
      pkey[pos] = (e << 6) | (k & 63);
    } else {
      bpay[pos] = make_int2(dsts[e] | ((k & 63) << 20), __float_as_int(vals[e]));
    }
  }
}

// ============================ embed bucket-sum ============================
__global__ __launch_bounds__(256) void k_embed_agg(
    const int* __restrict__ pkey, const float* __restrict__ edge_attr,
    const int* __restrict__ bstart, float* __restrict__ agg8, int N) {
  __shared__ float lds[FE][64];
  int b = blockIdx.x, tid = threadIdx.x;
  for (int i = tid; i < FE * 64; i += 256) ((float*)lds)[i] = 0.f;
  __syncthreads();
  int s = bstart[b], t = bstart[b + 1];
  for (int i = s + tid; i < t; i += 256) {
    int pk = pkey[i];
    int e = pk >> 6, slot = pk & 63;
    const float4* ea = (const float4*)(edge_attr + (size_t)e * FE);
    float4 a = ea[0], b4 = ea[1];
    atomicAdd(&lds[0][slot], a.x);  atomicAdd(&lds[1][slot], a.y);
    atomicAdd(&lds[2][slot], a.z);  atomicAdd(&lds[3][slot], a.w);
    atomicAdd(&lds[4][slot], b4.x); atomicAdd(&lds[5][slot], b4.y);
    atomicAdd(&lds[6][slot], b4.z); atomicAdd(&lds[7][slot], b4.w);
  }
  __syncthreads();
  int node0 = b * 64;
  for (int i = tid; i < 64 * FE; i += 256) {
    int n = node0 + (i >> 3);
    if (n < N) agg8[(size_t)n * FE + (i & 7)] = lds[i & 7][i >> 3];
  }
}

// ============================ pass-2 for adj sort ============================
__global__ __launch_bounds__(256) void k_p2(
    const int2* __restrict__ bpay, const int* __restrict__ bstart,
    int* __restrict__ offs, int2* __restrict__ payF, int N, int E) {
  __shared__ int cnt[64], scn[64], cur[64];
  int b = blockIdx.x, tid = threadIdx.x;
  int s = bstart[b], t = bstart[b + 1];
  if (tid < 64) cnt[tid] = 0;
  __syncthreads();
  for (int i = s + tid; i < t; i += 256) atomicAdd(&cnt[(bpay[i].x >> 20) & 63], 1);
  __syncthreads();
  if (tid < 64) scn[tid] = cnt[tid];
  __syncthreads();
  for (int off = 1; off < 64; off <<= 1) {
    int v = 0;
    if (tid < 64 && tid >= off) v = scn[tid - off];
    __syncthreads();
    if (tid < 64 && tid >= off) scn[tid] += v;
    __syncthreads();
  }
  if (tid < 64) {
    int excl = s + scn[tid] - cnt[tid];
    cur[tid] = excl;
    int node = b * 64 + tid;
    if (node < N) offs[node] = excl;
  }
  if (b == 0 && tid == 0) offs[N] = E;
  __syncthreads();
  for (int i = s + tid; i < t; i += 256) {
    int2 p = bpay[i];
    int slot = (p.x >> 20) & 63;
    int pos = atomicAdd(&cur[slot], 1);
    payF[pos] = make_int2(p.x & 0xFFFFF, p.y);
  }
}

// ============================ embed h ============================
__global__ __launch_bounds__(256) void k_embed_h(
    const float* __restrict__ node_attr, const float* __restrict__ Wn,
    const float* __restrict__ We8, const float* __restrict__ b,
    const float* __restrict__ agg8, float* __restrict__ h, int N) {
  __shared__ float Ws[FN * H];
  __shared__ float Es[FE * H];
  __shared__ float na[2][FN];
  __shared__ float a8[2][FE];
  for (int i = threadIdx.x; i < FN * H; i += 256) Ws[i] = Wn[i];
  for (int i = threadIdx.x; i < FE * H; i += 256) Es[i] = We8[i];
  int lane = threadIdx.x & 127;
  int sub  = threadIdx.x >> 7;
  for (int n0 = blockIdx.x * 2; n0 < N; n0 += gridDim.x * 2) {
    int n = n0 + sub;
    __syncthreads();
    if (n < N) {
      if (lane < FN) na[sub][lane] = node_attr[(size_t)n * FN + lane];
      else if (lane < FN + FE) a8[sub][lane - FN] = agg8[(size_t)n * FE + (lane - FN)];
    }
    __syncthreads();
    if (n < N) {
      float acc = b[lane];
#pragma unroll
      for (int k = 0; k < FN; k++) acc += na[sub][k] * Ws[k * H + lane];
#pragma unroll
      for (int k = 0; k < FE; k++) acc += a8[sub][k] * Es[k * H + lane];
      h[(size_t)n * H + lane] = fmaxf(acc, 0.f);
    }
  }
}

// ============================ LDS GEMM [N,128]@[128,128]+b ============================
// Round-2 geometry (known lean: 64x128 tile, 8 rows x 4 cols/thread, acc=32 VGPR)
// + register prefetch of the next K-chunk (6 float4 = 24 VGPR) to hide global
// latency that made round-4's version barrier-drain-bound. ~100 VGPR total.
// (128x128 tile spilled at both (256,3) and free allocation — rounds 6/7.)
template <int RELU_OUT>
__global__ __launch_bounds__(256) void k_gemm(
    const float* __restrict__ in, const float* __restrict__ W,
    const float* __restrict__ bias, float* __restrict__ out, int N) {
  __shared__ float4 Ws4[32 * 32];   // [k(0..31)][col4(0..31)]  16 KB
  __shared__ float4 hs4[64 * 9];    // [row][k4(0..7)] pad->9    9 KB
  int tid = threadIdx.x;
  int c  = tid & 31;                // col4
  int rg = tid >> 5;                // rows rg + 8*i
  int rowBase = blockIdx.x * 64;
  const float4* in4 = (const float4*)in;   // [N][32]
  const float4* Wg4 = (const float4*)W;    // [128][32]

  float4 acc[8];
#pragma unroll
  for (int i = 0; i < 8; i++) acc[i] = make_float4(0.f, 0.f, 0.f, 0.f);

  // staging assignments: Ws gets 4 float4/thread, hs gets 2 float4/thread
  int srow[2], skq[2];
#pragma unroll
  for (int j = 0; j < 2; j++) {
    int q = tid + 256 * j;              // 0..511
    int r = rowBase + (q >> 3);         // row in tile 0..63
    srow[j] = (r < N) ? r : (N - 1);    // clamp for safe load; store guarded
    skq[j] = q & 7;
  }

  float4 wpre[4], hpre[2];
#pragma unroll
  for (int j = 0; j < 4; j++) wpre[j] = Wg4[tid + 256 * j];              // chunk 0
#pragma unroll
  for (int j = 0; j < 2; j++) hpre[j] = in4[(size_t)srow[j] * 32 + skq[j]];

  for (int kk = 0; kk < 4; kk++) {
    if (kk) __syncthreads();            // previous compute done reading LDS
#pragma unroll
    for (int j = 0; j < 4; j++) Ws4[tid + 256 * j] = wpre[j];
#pragma unroll
    for (int j = 0; j < 2; j++) {
      int q = tid + 256 * j;
      hs4[(q >> 3) * 9 + (q & 7)] = hpre[j];
    }
    __syncthreads();
    if (kk < 3) {
#pragma unroll
      for (int j = 0; j < 4; j++)
        wpre[j] = Wg4[(kk + 1) * 1024 + tid + 256 * j];
#pragma unroll
      for (int j = 0; j < 2; j++)
        hpre[j] = in4[(size_t)srow[j] * 32 + (kk + 1) * 8 + skq[j]];
    }
#pragma unroll
    for (int k4 = 0; k4 < 8; k4++) {
      float4 w0 = Ws4[(k4 * 4 + 0) * 32 + c];
      float4 w1 = Ws4[(k4 * 4 + 1) * 32 + c];
      float4 w2 = Ws4[(k4 * 4 + 2) * 32 + c];
      float4 w3 = Ws4[(k4 * 4 + 3) * 32 + c];
#pragma unroll
      for (int i = 0; i < 8; i++) {
        float4 hv = hs4[(rg + 8 * i) * 9 + k4];
        acc[i].x += hv.x * w0.x + hv.y * w1.x + hv.z * w2.x + hv.w * w3.x;
        acc[i].y += hv.x * w0.y + hv.y * w1.y + hv.z * w2.y + hv.w * w3.y;
        acc[i].z += hv.x * w0.z + hv.y * w1.z + hv.z * w2.z + hv.w * w3.z;
        acc[i].w += hv.x * w0.w + hv.y * w1.w + hv.z * w2.w + hv.w * w3.w;
      }
    }
  }

  float4 bv = ((const float4*)bias)[c];
#pragma unroll
  for (int i = 0; i < 8; i++) {
    int row = rowBase + rg + 8 * i;
    if (row < N) {
      float4 o = make_float4(acc[i].x + bv.x, acc[i].y + bv.y,
                             acc[i].z + bv.z, acc[i].w + bv.w);
      if (RELU_OUT) {
        o.x = fmaxf(o.x, 0.f); o.y = fmaxf(o.y, 0.f);
        o.z = fmaxf(o.z, 0.f); o.w = fmaxf(o.w, 0.f);
      }
      ((float4*)out)[(size_t)row * 32 + c] = o;
    }
  }
}

// ============================ GCN gather-aggregate ============================
__global__ __launch_bounds__(256) void k_gcn_gather(
    const float* __restrict__ hw, const int* __restrict__ offs,
    const int2* __restrict__ pay, float* __restrict__ out, int N) {
  int n = blockIdx.x * 8 + (threadIdx.x >> 5);
  if (n >= N) return;
  int c = threadIdx.x & 31;
  int s = offs[n], t = offs[n + 1];
  float4 acc = make_float4(0.f, 0.f, 0.f, 0.f);
  for (int i = s; i < t; i++) {
    int2 p = pay[i];
    float v = __int_as_float(p.y);
    float4 hv = ((const float4*)hw)[(size_t)p.x * 32 + c];
    acc.x += v * hv.x; acc.y += v * hv.y;
    acc.z += v * hv.z; acc.w += v * hv.w;
  }
  float4 o = make_float4(fmaxf(acc.x, 0.f), fmaxf(acc.y, 0.f),
                         fmaxf(acc.z, 0.f), fmaxf(acc.w, 0.f));
  ((float4*)(out + (size_t)n * H))[c] = o;
}

// ============================ pool + predictor ============================
__global__ __launch_bounds__(256) void k_gbounds(
    const int* __restrict__ batch, int* __restrict__ gstart, int N, int G) {
  int n = blockIdx.x * 256 + threadIdx.x;
  if (n > N) return;
  if (n == 0) {
    for (int g = 0; g <= batch[0]; g++) gstart[g] = 0;
  } else if (n == N) {
    for (int g = batch[N - 1] + 1; g <= G; g++) gstart[g] = N;
  } else {
    int b0 = batch[n - 1], b1 = batch[n];
    for (int g = b0 + 1; g <= b1; g++) gstart[g] = n;
  }
}

__global__ __launch_bounds__(128) void k_pool_seg(
    const float* __restrict__ h, const int* __restrict__ gstart,
    float* __restrict__ fp, int G) {
  int g = blockIdx.x;
  int j = threadIdx.x;
  int s = gstart[g], t = gstart[g + 1];
  float acc = 0.f;
  for (int n = s; n < t; n++) acc += h[(size_t)n * H + j];
  fp[(size_t)g * H + j] = acc;
}

__global__ __launch_bounds__(256) void k_pred2(
    const float* __restrict__ z, const float* __restrict__ Wp2,
    const float* __restrict__ bp2, float* __restrict__ out, int G) {
  int g = blockIdx.x * 4 + (threadIdx.x >> 6);
  if (g >= G) return;
  int l = threadIdx.x & 63;
  float2 zv = ((const float2*)z)[(size_t)g * 64 + l];
  float2 wv = ((const float2*)Wp2)[l];
  float v = zv.x * wv.x + zv.y * wv.y;
#pragma unroll
  for (int off = 32; off > 0; off >>= 1) v += __shfl_down(v, off, 64);
  if (l == 0) out[g] = v + bp2[0];
}

// ============================ launch ============================
extern "C" void kernel_launch(void* const* d_in, const int* in_sizes, int n_in,
                              void* d_out, int out_size, void* d_ws, size_t ws_size,
                              hipStream_t stream) {
  const float* node_attr  = (const float*)d_in[0];
  const float* edge_attr  = (const float*)d_in[1];
  const int*   edge_index = (const int*)d_in[2];
  const int*   adj_index  = (const int*)d_in[3];
  const float* adj_value  = (const float*)d_in[4];
  const int*   batch      = (const int*)d_in[5];
  const float* W_node  = (const float*)d_in[6];
  const float* W_edge  = (const float*)d_in[7];
  const float* b_embed = (const float*)d_in[8];
  const float* W1 = (const float*)d_in[9];
  const float* b1 = (const float*)d_in[10];
  const float* W2 = (const float*)d_in[11];
  const float* b2 = (const float*)d_in[12];
  const float* W3 = (const float*)d_in[13];
  const float* b3 = (const float*)d_in[14];
  const float* Wp1 = (const float*)d_in[15];
  const float* bp1 = (const float*)d_in[16];
  const float* Wp2 = (const float*)d_in[17];
  const float* bp2 = (const float*)d_in[18];
  float* out = (float*)d_out;

  const int E = in_sizes[4];           // 1,600,000
  const int N = in_sizes[5];           // 100,000
  const int G = out_size;              // 2048
  const int nbuk = (N + 63) >> 6;      // 1563
  const int p1b = (E + 8191) / 8192;

  // ---- workspace layout ----
  float* A     = (float*)d_ws;                       // N*H
  float* B     = A + (size_t)N * H;                  // N*H
  int2*  payF  = (int2*)(B + (size_t)N * H);         // E
  float* fpool = (float*)(payF + E);                 // G*H
  int*   bcnt1 = (int*)(fpool + (size_t)G * H);      // nbuk  } one memset
  int*   bcnt2 = bcnt1 + nbuk;                       // nbuk  }
  int*   bst1  = bcnt2 + nbuk;                       // nbuk+1
  int*   gcur1 = bst1 + nbuk + 1;                    // nbuk
  int*   bst2  = gcur1 + nbuk;                       // nbuk+1
  int*   gcur2 = bst2 + nbuk + 1;                    // nbuk
  int*   offs2 = gcur2 + nbuk;                       // N+1
  int*   gstart= offs2 + N + 1;                      // G+1
  // transient aliases (lifetimes by launch order):
  float* agg8  = A;                                  // N*FE; dead after embed_h
  int*   pkey  = (int*)B;                            // E ints; dead after embed_agg
  int2*  bpay2 = (int2*)(((int*)B) + E);             // E int2; dead after p2
  float* zbuf  = A;                                  // G*H; A free after last gather

  // ---- histograms + scans (both sorts) ----
  hipMemsetAsync(bcnt1, 0, (size_t)2 * nbuk * sizeof(int), stream);
  k_hist2<<<512, 256, 0, stream>>>(edge_index + E, adj_index, bcnt1, bcnt2, E, nbuk);
  k_scan<<<1, 1024, 0, stream>>>(bcnt1, bst1, gcur1, bcnt2, bst2, gcur2, nbuk);

  // ---- pass-1 scatters ----
  k_p1_scatter<1><<<p1b, 256, 0, stream>>>(edge_index + E, nullptr, nullptr,
                                           gcur1, pkey, nullptr, E, nbuk);
  k_p1_scatter<0><<<p1b, 256, 0, stream>>>(adj_index, adj_index + E, adj_value,
                                           gcur2, nullptr, bpay2, E, nbuk);

  // ---- embed agg + adj pass-2 ----
  k_embed_agg<<<nbuk, 256, 0, stream>>>(pkey, edge_attr, bst1, agg8, N);
  k_p2<<<nbuk, 256, 0, stream>>>(bpay2, bst2, offs2, payF, N, E);

  // ---- embed h -> B ----
  k_embed_h<<<4096, 256, 0, stream>>>(node_attr, W_node, W_edge, b_embed, agg8, B, N);

  k_gbounds<<<(N + 256) / 256, 256, 0, stream>>>(batch, gstart, N, G);

  // ---- 3 GCN layers: A = B@W+b ; B = relu(gather(A)) ----
  int gemm_blocks = (N + 63) / 64;
  int agb = (N + 7) / 8;
  k_gemm<0><<<gemm_blocks, 256, 0, stream>>>(B, W1, b1, A, N);
  k_gcn_gather<<<agb, 256, 0, stream>>>(A, offs2, payF, B, N);
  k_gemm<0><<<gemm_blocks, 256, 0, stream>>>(B, W2, b2, A, N);
  k_gcn_gather<<<agb, 256, 0, stream>>>(A, offs2, payF, B, N);
  k_gemm<0><<<gemm_blocks, 256, 0, stream>>>(B, W3, b3, A, N);
  k_gcn_gather<<<agb, 256, 0, stream>>>(A, offs2, payF, B, N);

  // ---- pool + predictor ----
  k_pool_seg<<<G, 128, 0, stream>>>(B, gstart, fpool, G);
  k_gemm<1><<<G / 64, 256, 0, stream>>>(fpool, Wp1, bp1, zbuf, G);
  k_pred2<<<(G + 3) / 4, 256, 0, stream>>>(zbuf, Wp2, bp2, out, G);
}

// Round 9
// 990.138 us; speedup vs baseline: 3.7979x; 1.1797x over previous
//
#include <hip/hip_runtime.h>

#define H 128
#define FN 16
#define FE 8
#define NBUK_MAX 1600   // buckets = ceil(N/64) = 1563 for N=100k

// ============================ histogram (both sorts fused) ============================
__global__ __launch_bounds__(256) void k_hist2(
    const int* __restrict__ k1, const int* __restrict__ k2,
    int* __restrict__ bcnt1, int* __restrict__ bcnt2, int E, int nbuk) {
  __shared__ int h1[NBUK_MAX], h2[NBUK_MAX];
  for (int i = threadIdx.x; i < nbuk; i += 256) { h1[i] = 0; h2[i] = 0; }
  __syncthreads();
  for (int e = blockIdx.x * 256 + threadIdx.x; e < E; e += gridDim.x * 256) {
    atomicAdd(&h1[k1[e] >> 6], 1);
    atomicAdd(&h2[k2[e] >> 6], 1);
  }
  __syncthreads();
  for (int i = threadIdx.x; i < nbuk; i += 256) {
    if (h1[i]) atomicAdd(&bcnt1[i], h1[i]);
    if (h2[i]) atomicAdd(&bcnt2[i], h2[i]);
  }
}

// ============================ single-block dual scan ============================
__global__ __launch_bounds__(1024) void k_scan(
    const int* __restrict__ cnt1, int* __restrict__ st1, int* __restrict__ gc1,
    const int* __restrict__ cnt2, int* __restrict__ st2, int* __restrict__ gc2,
    int nbuk) {
  __shared__ int s[1024];
  int tid = threadIdx.x;
  for (int pass = 0; pass < 2; pass++) {
    const int* cnt = pass ? cnt2 : cnt1;
    int* st = pass ? st2 : st1;
    int* gc = pass ? gc2 : gc1;
    int run = 0;
    for (int half = 0; half * 1024 < nbuk; half++) {
      int i = half * 1024 + tid;
      int v = (i < nbuk) ? cnt[i] : 0;
      s[tid] = v; __syncthreads();
      for (int off = 1; off < 1024; off <<= 1) {
        int t = (tid >= off) ? s[tid - off] : 0;
        __syncthreads();
        s[tid] += t;
        __syncthreads();
      }
      int excl = run + s[tid] - v;
      if (i < nbuk) { st[i] = excl; gc[i] = excl; }
      run += s[1023];
      __syncthreads();
    }
    if (tid == 0) st[nbuk] = run;
    __syncthreads();
  }
}

// ============================ pass-1 bucket scatter ============================
template <int PACKED>
__global__ __launch_bounds__(256) void k_p1_scatter(
    const int* __restrict__ key, const int* __restrict__ dsts,
    const float* __restrict__ vals, int* __restrict__ gcur,
    int* __restrict__ pkey, int2* __restrict__ bpay, int E, int nbuk) {
  __shared__ int hc[NBUK_MAX];
  int tid = threadIdx.x;
  int c0 = blockIdx.x * 8192;
  int c1 = min(c0 + 8192, E);
  for (int i = tid; i < nbuk; i += 256) hc[i] = 0;
  __syncthreads();
  for (int e = c0 + tid; e < c1; e += 256)
    atomicAdd(&hc[key[e] >> 6], 1);
  __syncthreads();
  for (int i = tid; i < nbuk; i += 256) {
    int c = hc[i];
    if (c) hc[i] = atomicAdd(&gcur[i], c);
  }
  __syncthreads();
  for (int e = c0 + tid; e < c1; e += 256) {
    int k = key[e];
    int pos = atomicAdd(&hc[k >> 6], 1);
    if (PACKED) {
      pkey[pos] = (e << 6) | (k & 63);
    } else {
      bpay[pos] = make_int2(dsts[e] | ((k & 63) << 20), __float_as_int(vals[e]));
    }
  }
}

// ============================ embed bucket-sum ============================
__global__ __launch_bounds__(256) void k_embed_agg(
    const int* __restrict__ pkey, const float* __restrict__ edge_attr,
    const int* __restrict__ bstart, float* __restrict__ agg8, int N) {
  __shared__ float lds[FE][64];
  int b = blockIdx.x, tid = threadIdx.x;
  for (int i = tid; i < FE * 64; i += 256) ((float*)lds)[i] = 0.f;
  __syncthreads();
  int s = bstart[b], t = bstart[b + 1];
  for (int i = s + tid; i < t; i += 256) {
    int pk = pkey[i];
    int e = pk >> 6, slot = pk & 63;
    const float4* ea = (const float4*)(edge_attr + (size_t)e * FE);
    float4 a = ea[0], b4 = ea[1];
    atomicAdd(&lds[0][slot], a.x);  atomicAdd(&lds[1][slot], a.y);
    atomicAdd(&lds[2][slot], a.z);  atomicAdd(&lds[3][slot], a.w);
    atomicAdd(&lds[4][slot], b4.x); atomicAdd(&lds[5][slot], b4.y);
    atomicAdd(&lds[6][slot], b4.z); atomicAdd(&lds[7][slot], b4.w);
  }
  __syncthreads();
  int node0 = b * 64;
  for (int i = tid; i < 64 * FE; i += 256) {
    int n = node0 + (i >> 3);
    if (n < N) agg8[(size_t)n * FE + (i & 7)] = lds[i & 7][i >> 3];
  }
}

// ============================ pass-2 for adj sort ============================
__global__ __launch_bounds__(256) void k_p2(
    const int2* __restrict__ bpay, const int* __restrict__ bstart,
    int* __restrict__ offs, int2* __restrict__ payF, int N, int E) {
  __shared__ int cnt[64], scn[64], cur[64];
  int b = blockIdx.x, tid = threadIdx.x;
  int s = bstart[b], t = bstart[b + 1];
  if (tid < 64) cnt[tid] = 0;
  __syncthreads();
  for (int i = s + tid; i < t; i += 256) atomicAdd(&cnt[(bpay[i].x >> 20) & 63], 1);
  __syncthreads();
  if (tid < 64) scn[tid] = cnt[tid];
  __syncthreads();
  for (int off = 1; off < 64; off <<= 1) {
    int v = 0;
    if (tid < 64 && tid >= off) v = scn[tid - off];
    __syncthreads();
    if (tid < 64 && tid >= off) scn[tid] += v;
    __syncthreads();
  }
  if (tid < 64) {
    int excl = s + scn[tid] - cnt[tid];
    cur[tid] = excl;
    int node = b * 64 + tid;
    if (node < N) offs[node] = excl;
  }
  if (b == 0 && tid == 0) offs[N] = E;
  __syncthreads();
  for (int i = s + tid; i < t; i += 256) {
    int2 p = bpay[i];
    int slot = (p.x >> 20) & 63;
    int pos = atomicAdd(&cur[slot], 1);
    payF[pos] = make_int2(p.x & 0xFFFFF, p.y);
  }
}

// ============================ embed h ============================
__global__ __launch_bounds__(256) void k_embed_h(
    const float* __restrict__ node_attr, const float* __restrict__ Wn,
    const float* __restrict__ We8, const float* __restrict__ b,
    const float* __restrict__ agg8, float* __restrict__ h, int N) {
  __shared__ float Ws[FN * H];
  __shared__ float Es[FE * H];
  __shared__ float na[2][FN];
  __shared__ float a8[2][FE];
  for (int i = threadIdx.x; i < FN * H; i += 256) Ws[i] = Wn[i];
  for (int i = threadIdx.x; i < FE * H; i += 256) Es[i] = We8[i];
  int lane = threadIdx.x & 127;
  int sub  = threadIdx.x >> 7;
  for (int n0 = blockIdx.x * 2; n0 < N; n0 += gridDim.x * 2) {
    int n = n0 + sub;
    __syncthreads();
    if (n < N) {
      if (lane < FN) na[sub][lane] = node_attr[(size_t)n * FN + lane];
      else if (lane < FN + FE) a8[sub][lane - FN] = agg8[(size_t)n * FE + (lane - FN)];
    }
    __syncthreads();
    if (n < N) {
      float acc = b[lane];
#pragma unroll
      for (int k = 0; k < FN; k++) acc += na[sub][k] * Ws[k * H + lane];
#pragma unroll
      for (int k = 0; k < FE; k++) acc += a8[sub][k] * Es[k * H + lane];
      h[(size_t)n * H + lane] = fmaxf(acc, 0.f);
    }
  }
}

// ============================ GEMM [N,128]@[128,128]+b ============================
// Barrier-free K-loop: the WHOLE 64-row input tile (64x128 fp32 = 32 KB) is
// staged in LDS once -> ONE syncthreads. W is read per-lane coalesced straight
// from global (64 KB, L1/L2-resident; round-5 showed W-from-global is cheap —
// the `in` broadcasts were the problem, fixed here by LDS).
// No register prefetch: rounds 6-8 showed prefetch inflates VGPR (156-256),
// collapses occupancy, and loses to plain staging on this compiler.
template <int RELU_OUT>
__global__ __launch_bounds__(256) void k_gemm(
    const float* __restrict__ in, const float* __restrict__ W,
    const float* __restrict__ bias, float* __restrict__ out, int N) {
  __shared__ float4 hs4[64 * 32];   // [row][k4] 32 KB
  int tid = threadIdx.x;
  int c  = tid & 31;                // col4
  int rg = tid >> 5;                // rows rg + 8*i
  int rowBase = blockIdx.x * 64;
  const float4* in4 = (const float4*)in;   // [N][32]
  const float4* W4  = (const float4*)W;    // [128][32]

  // stage full tile: 8 float4 per thread, coalesced
#pragma unroll
  for (int j = 0; j < 8; j++) {
    int q = tid + 256 * j;          // 0..2047
    int r = rowBase + (q >> 5);
    int rr = (r < N) ? r : (N - 1); // clamp for safe load; store guarded
    hs4[q] = in4[(size_t)rr * 32 + (q & 31)];
  }
  __syncthreads();

  float4 acc[8];
#pragma unroll
  for (int i = 0; i < 8; i++) acc[i] = make_float4(0.f, 0.f, 0.f, 0.f);

#pragma unroll 2
  for (int k = 0; k < 32; k++) {    // k4 over full K=128
    float4 w0 = W4[(k * 4 + 0) * 32 + c];
    float4 w1 = W4[(k * 4 + 1) * 32 + c];
    float4 w2 = W4[(k * 4 + 2) * 32 + c];
    float4 w3 = W4[(k * 4 + 3) * 32 + c];
#pragma unroll
    for (int i = 0; i < 8; i++) {
      float4 hv = hs4[(rg + 8 * i) * 32 + k];
      acc[i].x += hv.x * w0.x + hv.y * w1.x + hv.z * w2.x + hv.w * w3.x;
      acc[i].y += hv.x * w0.y + hv.y * w1.y + hv.z * w2.y + hv.w * w3.y;
      acc[i].z += hv.x * w0.z + hv.y * w1.z + hv.z * w2.z + hv.w * w3.z;
      acc[i].w += hv.x * w0.w + hv.y * w1.w + hv.z * w2.w + hv.w * w3.w;
    }
  }

  float4 bv = ((const float4*)bias)[c];
#pragma unroll
  for (int i = 0; i < 8; i++) {
    int row = rowBase + rg + 8 * i;
    if (row < N) {
      float4 o = make_float4(acc[i].x + bv.x, acc[i].y + bv.y,
                             acc[i].z + bv.z, acc[i].w + bv.w);
      if (RELU_OUT) {
        o.x = fmaxf(o.x, 0.f); o.y = fmaxf(o.y, 0.f);
        o.z = fmaxf(o.z, 0.f); o.w = fmaxf(o.w, 0.f);
      }
      ((float4*)out)[(size_t)row * 32 + c] = o;
    }
  }
}

// ============================ GCN gather-aggregate ============================
__global__ __launch_bounds__(256) void k_gcn_gather(
    const float* __restrict__ hw, const int* __restrict__ offs,
    const int2* __restrict__ pay, float* __restrict__ out, int N) {
  int n = blockIdx.x * 8 + (threadIdx.x >> 5);
  if (n >= N) return;
  int c = threadIdx.x & 31;
  int s = offs[n], t = offs[n + 1];
  float4 acc = make_float4(0.f, 0.f, 0.f, 0.f);
  for (int i = s; i < t; i++) {
    int2 p = pay[i];
    float v = __int_as_float(p.y);
    float4 hv = ((const float4*)hw)[(size_t)p.x * 32 + c];
    acc.x += v * hv.x; acc.y += v * hv.y;
    acc.z += v * hv.z; acc.w += v * hv.w;
  }
  float4 o = make_float4(fmaxf(acc.x, 0.f), fmaxf(acc.y, 0.f),
                         fmaxf(acc.z, 0.f), fmaxf(acc.w, 0.f));
  ((float4*)(out + (size_t)n * H))[c] = o;
}

// ============================ pool + predictor ============================
__global__ __launch_bounds__(256) void k_gbounds(
    const int* __restrict__ batch, int* __restrict__ gstart, int N, int G) {
  int n = blockIdx.x * 256 + threadIdx.x;
  if (n > N) return;
  if (n == 0) {
    for (int g = 0; g <= batch[0]; g++) gstart[g] = 0;
  } else if (n == N) {
    for (int g = batch[N - 1] + 1; g <= G; g++) gstart[g] = N;
  } else {
    int b0 = batch[n - 1], b1 = batch[n];
    for (int g = b0 + 1; g <= b1; g++) gstart[g] = n;
  }
}

__global__ __launch_bounds__(128) void k_pool_seg(
    const float* __restrict__ h, const int* __restrict__ gstart,
    float* __restrict__ fp, int G) {
  int g = blockIdx.x;
  int j = threadIdx.x;
  int s = gstart[g], t = gstart[g + 1];
  float acc = 0.f;
  for (int n = s; n < t; n++) acc += h[(size_t)n * H + j];
  fp[(size_t)g * H + j] = acc;
}

__global__ __launch_bounds__(256) void k_pred2(
    const float* __restrict__ z, const float* __restrict__ Wp2,
    const float* __restrict__ bp2, float* __restrict__ out, int G) {
  int g = blockIdx.x * 4 + (threadIdx.x >> 6);
  if (g >= G) return;
  int l = threadIdx.x & 63;
  float2 zv = ((const float2*)z)[(size_t)g * 64 + l];
  float2 wv = ((const float2*)Wp2)[l];
  float v = zv.x * wv.x + zv.y * wv.y;
#pragma unroll
  for (int off = 32; off > 0; off >>= 1) v += __shfl_down(v, off, 64);
  if (l == 0) out[g] = v + bp2[0];
}

// ============================ launch ============================
extern "C" void kernel_launch(void* const* d_in, const int* in_sizes, int n_in,
                              void* d_out, int out_size, void* d_ws, size_t ws_size,
                              hipStream_t stream) {
  const float* node_attr  = (const float*)d_in[0];
  const float* edge_attr  = (const float*)d_in[1];
  const int*   edge_index = (const int*)d_in[2];
  const int*   adj_index  = (const int*)d_in[3];
  const float* adj_value  = (const float*)d_in[4];
  const int*   batch      = (const int*)d_in[5];
  const float* W_node  = (const float*)d_in[6];
  const float* W_edge  = (const float*)d_in[7];
  const float* b_embed = (const float*)d_in[8];
  const float* W1 = (const float*)d_in[9];
  const float* b1 = (const float*)d_in[10];
  const float* W2 = (const float*)d_in[11];
  const float* b2 = (const float*)d_in[12];
  const float* W3 = (const float*)d_in[13];
  const float* b3 = (const float*)d_in[14];
  const float* Wp1 = (const float*)d_in[15];
  const float* bp1 = (const float*)d_in[16];
  const float* Wp2 = (const float*)d_in[17];
  const float* bp2 = (const float*)d_in[18];
  float* out = (float*)d_out;

  const int E = in_sizes[4];           // 1,600,000
  const int N = in_sizes[5];           // 100,000
  const int G = out_size;              // 2048
  const int nbuk = (N + 63) >> 6;      // 1563
  const int p1b = (E + 8191) / 8192;

  // ---- workspace layout ----
  float* A     = (float*)d_ws;                       // N*H
  float* B     = A + (size_t)N * H;                  // N*H
  int2*  payF  = (int2*)(B + (size_t)N * H);         // E
  float* fpool = (float*)(payF + E);                 // G*H
  int*   bcnt1 = (int*)(fpool + (size_t)G * H);      // nbuk  } one memset
  int*   bcnt2 = bcnt1 + nbuk;                       // nbuk  }
  int*   bst1  = bcnt2 + nbuk;                       // nbuk+1
  int*   gcur1 = bst1 + nbuk + 1;                    // nbuk
  int*   bst2  = gcur1 + nbuk;                       // nbuk+1
  int*   gcur2 = bst2 + nbuk + 1;                    // nbuk
  int*   offs2 = gcur2 + nbuk;                       // N+1
  int*   gstart= offs2 + N + 1;                      // G+1
  // transient aliases (lifetimes by launch order):
  float* agg8  = A;                                  // N*FE; dead after embed_h
  int*   pkey  = (int*)B;                            // E ints; dead after embed_agg
  int2*  bpay2 = (int2*)(((int*)B) + E);             // E int2; dead after p2
  float* zbuf  = A;                                  // G*H; A free after last gather

  // ---- histograms + scans (both sorts) ----
  hipMemsetAsync(bcnt1, 0, (size_t)2 * nbuk * sizeof(int), stream);
  k_hist2<<<512, 256, 0, stream>>>(edge_index + E, adj_index, bcnt1, bcnt2, E, nbuk);
  k_scan<<<1, 1024, 0, stream>>>(bcnt1, bst1, gcur1, bcnt2, bst2, gcur2, nbuk);

  // ---- pass-1 scatters ----
  k_p1_scatter<1><<<p1b, 256, 0, stream>>>(edge_index + E, nullptr, nullptr,
                                           gcur1, pkey, nullptr, E, nbuk);
  k_p1_scatter<0><<<p1b, 256, 0, stream>>>(adj_index, adj_index + E, adj_value,
                                           gcur2, nullptr, bpay2, E, nbuk);

  // ---- embed agg + adj pass-2 ----
  k_embed_agg<<<nbuk, 256, 0, stream>>>(pkey, edge_attr, bst1, agg8, N);
  k_p2<<<nbuk, 256, 0, stream>>>(bpay2, bst2, offs2, payF, N, E);

  // ---- embed h -> B ----
  k_embed_h<<<4096, 256, 0, stream>>>(node_attr, W_node, W_edge, b_embed, agg8, B, N);

  k_gbounds<<<(N + 256) / 256, 256, 0, stream>>>(batch, gstart, N, G);

  // ---- 3 GCN layers: A = B@W+b ; B = relu(gather(A)) ----
  int gemm_blocks = (N + 63) / 64;
  int agb = (N + 7) / 8;
  k_gemm<0><<<gemm_blocks, 256, 0, stream>>>(B, W1, b1, A, N);
  k_gcn_gather<<<agb, 256, 0, stream>>>(A, offs2, payF, B, N);
  k_gemm<0><<<gemm_blocks, 256, 0, stream>>>(B, W2, b2, A, N);
  k_gcn_gather<<<agb, 256, 0, stream>>>(A, offs2, payF, B, N);
  k_gemm<0><<<gemm_blocks, 256, 0, stream>>>(B, W3, b3, A, N);
  k_gcn_gather<<<agb, 256, 0, stream>>>(A, offs2, payF, B, N);

  // ---- pool + predictor ----
  k_pool_seg<<<G, 128, 0, stream>>>(B, gstart, fpool, G);
  k_gemm<1><<<G / 64, 256, 0, stream>>>(fpool, Wp1, bp1, zbuf, G);
  k_pred2<<<(G + 3) / 4, 256, 0, stream>>>(zbuf, Wp2, bp2, out, G);
}

// Round 10
// 967.969 us; speedup vs baseline: 3.8849x; 1.0229x over previous
//
#include <hip/hip_runtime.h>

#define H 128
#define FN 16
#define FE 8
#define NBUK_MAX 1600   // buckets = ceil(N/64) = 1563 for N=100k

// ============================ histogram (both sorts fused) ============================
__global__ __launch_bounds__(256) void k_hist2(
    const int* __restrict__ k1, const int* __restrict__ k2,
    int* __restrict__ bcnt1, int* __restrict__ bcnt2, int E, int nbuk) {
  __shared__ int h1[NBUK_MAX], h2[NBUK_MAX];
  for (int i = threadIdx.x; i < nbuk; i += 256) { h1[i] = 0; h2[i] = 0; }
  __syncthreads();
  for (int e = blockIdx.x * 256 + threadIdx.x; e < E; e += gridDim.x * 256) {
    atomicAdd(&h1[k1[e] >> 6], 1);
    atomicAdd(&h2[k2[e] >> 6], 1);
  }
  __syncthreads();
  for (int i = threadIdx.x; i < nbuk; i += 256) {
    if (h1[i]) atomicAdd(&bcnt1[i], h1[i]);
    if (h2[i]) atomicAdd(&bcnt2[i], h2[i]);
  }
}

// ============================ single-block dual scan ============================
__global__ __launch_bounds__(1024) void k_scan(
    const int* __restrict__ cnt1, int* __restrict__ st1, int* __restrict__ gc1,
    const int* __restrict__ cnt2, int* __restrict__ st2, int* __restrict__ gc2,
    int nbuk) {
  __shared__ int s[1024];
  int tid = threadIdx.x;
  for (int pass = 0; pass < 2; pass++) {
    const int* cnt = pass ? cnt2 : cnt1;
    int* st = pass ? st2 : st1;
    int* gc = pass ? gc2 : gc1;
    int run = 0;
    for (int half = 0; half * 1024 < nbuk; half++) {
      int i = half * 1024 + tid;
      int v = (i < nbuk) ? cnt[i] : 0;
      s[tid] = v; __syncthreads();
      for (int off = 1; off < 1024; off <<= 1) {
        int t = (tid >= off) ? s[tid - off] : 0;
        __syncthreads();
        s[tid] += t;
        __syncthreads();
      }
      int excl = run + s[tid] - v;
      if (i < nbuk) { st[i] = excl; gc[i] = excl; }
      run += s[1023];
      __syncthreads();
    }
    if (tid == 0) st[nbuk] = run;
    __syncthreads();
  }
}

// ============================ pass-1 bucket scatter ============================
template <int PACKED>
__global__ __launch_bounds__(256) void k_p1_scatter(
    const int* __restrict__ key, const int* __restrict__ dsts,
    const float* __restrict__ vals, int* __restrict__ gcur,
    int* __restrict__ pkey, int2* __restrict__ bpay, int E, int nbuk) {
  __shared__ int hc[NBUK_MAX];
  int tid = threadIdx.x;
  int c0 = blockIdx.x * 8192;
  int c1 = min(c0 + 8192, E);
  for (int i = tid; i < nbuk; i += 256) hc[i] = 0;
  __syncthreads();
  for (int e = c0 + tid; e < c1; e += 256)
    atomicAdd(&hc[key[e] >> 6], 1);
  __syncthreads();
  for (int i = tid; i < nbuk; i += 256) {
    int c = hc[i];
    if (c) hc[i] = atomicAdd(&gcur[i], c);
  }
  __syncthreads();
  for (int e = c0 + tid; e < c1; e += 256) {
    int k = key[e];
    int pos = atomicAdd(&hc[k >> 6], 1);
    if (PACKED) {
      pkey[pos] = (e << 6) | (k & 63);
    } else {
      bpay[pos] = make_int2(dsts[e] | ((k & 63) << 20), __float_as_int(vals[e]));
    }
  }
}

// ============================ embed bucket-sum ============================
__global__ __launch_bounds__(256) void k_embed_agg(
    const int* __restrict__ pkey, const float* __restrict__ edge_attr,
    const int* __restrict__ bstart, float* __restrict__ agg8, int N) {
  __shared__ float lds[FE][64];
  int b = blockIdx.x, tid = threadIdx.x;
  for (int i = tid; i < FE * 64; i += 256) ((float*)lds)[i] = 0.f;
  __syncthreads();
  int s = bstart[b], t = bstart[b + 1];
  int i = s + tid;
  // unrolled x2 for independent outstanding row loads
  for (; i + 256 < t; i += 512) {
    int pk0 = pkey[i], pk1 = pkey[i + 256];
    const float4* e0 = (const float4*)(edge_attr + (size_t)(pk0 >> 6) * FE);
    const float4* e1 = (const float4*)(edge_attr + (size_t)(pk1 >> 6) * FE);
    float4 a0 = e0[0], b0 = e0[1], a1 = e1[0], b1 = e1[1];
    int s0 = pk0 & 63, s1 = pk1 & 63;
    atomicAdd(&lds[0][s0], a0.x);  atomicAdd(&lds[1][s0], a0.y);
    atomicAdd(&lds[2][s0], a0.z);  atomicAdd(&lds[3][s0], a0.w);
    atomicAdd(&lds[4][s0], b0.x);  atomicAdd(&lds[5][s0], b0.y);
    atomicAdd(&lds[6][s0], b0.z);  atomicAdd(&lds[7][s0], b0.w);
    atomicAdd(&lds[0][s1], a1.x);  atomicAdd(&lds[1][s1], a1.y);
    atomicAdd(&lds[2][s1], a1.z);  atomicAdd(&lds[3][s1], a1.w);
    atomicAdd(&lds[4][s1], b1.x);  atomicAdd(&lds[5][s1], b1.y);
    atomicAdd(&lds[6][s1], b1.z);  atomicAdd(&lds[7][s1], b1.w);
  }
  for (; i < t; i += 256) {
    int pk = pkey[i];
    int e = pk >> 6, slot = pk & 63;
    const float4* ea = (const float4*)(edge_attr + (size_t)e * FE);
    float4 a = ea[0], b4 = ea[1];
    atomicAdd(&lds[0][slot], a.x);  atomicAdd(&lds[1][slot], a.y);
    atomicAdd(&lds[2][slot], a.z);  atomicAdd(&lds[3][slot], a.w);
    atomicAdd(&lds[4][slot], b4.x); atomicAdd(&lds[5][slot], b4.y);
    atomicAdd(&lds[6][slot], b4.z); atomicAdd(&lds[7][slot], b4.w);
  }
  __syncthreads();
  int node0 = b * 64;
  for (int j = tid; j < 64 * FE; j += 256) {
    int n = node0 + (j >> 3);
    if (n < N) agg8[(size_t)n * FE + (j & 7)] = lds[j & 7][j >> 3];
  }
}

// ============================ pass-2 for adj sort ============================
__global__ __launch_bounds__(256) void k_p2(
    const int2* __restrict__ bpay, const int* __restrict__ bstart,
    int* __restrict__ offs, int2* __restrict__ payF, int N, int E) {
  __shared__ int cnt[64], scn[64], cur[64];
  int b = blockIdx.x, tid = threadIdx.x;
  int s = bstart[b], t = bstart[b + 1];
  if (tid < 64) cnt[tid] = 0;
  __syncthreads();
  for (int i = s + tid; i < t; i += 256) atomicAdd(&cnt[(bpay[i].x >> 20) & 63], 1);
  __syncthreads();
  if (tid < 64) scn[tid] = cnt[tid];
  __syncthreads();
  for (int off = 1; off < 64; off <<= 1) {
    int v = 0;
    if (tid < 64 && tid >= off) v = scn[tid - off];
    __syncthreads();
    if (tid < 64 && tid >= off) scn[tid] += v;
    __syncthreads();
  }
  if (tid < 64) {
    int excl = s + scn[tid] - cnt[tid];
    cur[tid] = excl;
    int node = b * 64 + tid;
    if (node < N) offs[node] = excl;
  }
  if (b == 0 && tid == 0) offs[N] = E;
  __syncthreads();
  for (int i = s + tid; i < t; i += 256) {
    int2 p = bpay[i];
    int slot = (p.x >> 20) & 63;
    int pos = atomicAdd(&cur[slot], 1);
    payF[pos] = make_int2(p.x & 0xFFFFF, p.y);
  }
}

// ============================ embed h ============================
__global__ __launch_bounds__(256) void k_embed_h(
    const float* __restrict__ node_attr, const float* __restrict__ Wn,
    const float* __restrict__ We8, const float* __restrict__ b,
    const float* __restrict__ agg8, float* __restrict__ h, int N) {
  __shared__ float Ws[FN * H];
  __shared__ float Es[FE * H];
  __shared__ float na[2][FN];
  __shared__ float a8[2][FE];
  for (int i = threadIdx.x; i < FN * H; i += 256) Ws[i] = Wn[i];
  for (int i = threadIdx.x; i < FE * H; i += 256) Es[i] = We8[i];
  int lane = threadIdx.x & 127;
  int sub  = threadIdx.x >> 7;
  for (int n0 = blockIdx.x * 2; n0 < N; n0 += gridDim.x * 2) {
    int n = n0 + sub;
    __syncthreads();
    if (n < N) {
      if (lane < FN) na[sub][lane] = node_attr[(size_t)n * FN + lane];
      else if (lane < FN + FE) a8[sub][lane - FN] = agg8[(size_t)n * FE + (lane - FN)];
    }
    __syncthreads();
    if (n < N) {
      float acc = b[lane];
#pragma unroll
      for (int k = 0; k < FN; k++) acc += na[sub][k] * Ws[k * H + lane];
#pragma unroll
      for (int k = 0; k < FE; k++) acc += a8[sub][k] * Es[k * H + lane];
      h[(size_t)n * H + lane] = fmaxf(acc, 0.f);
    }
  }
}

// ============================ GEMM [N,128]@[128,128]+b ============================
// Single-sync structure (round 9: 990 us total, gemm fell out of top-5).
template <int RELU_OUT>
__global__ __launch_bounds__(256) void k_gemm(
    const float* __restrict__ in, const float* __restrict__ W,
    const float* __restrict__ bias, float* __restrict__ out, int N) {
  __shared__ float4 hs4[64 * 32];   // [row][k4] 32 KB
  int tid = threadIdx.x;
  int c  = tid & 31;                // col4
  int rg = tid >> 5;                // rows rg + 8*i
  int rowBase = blockIdx.x * 64;
  const float4* in4 = (const float4*)in;   // [N][32]
  const float4* W4  = (const float4*)W;    // [128][32]

#pragma unroll
  for (int j = 0; j < 8; j++) {
    int q = tid + 256 * j;          // 0..2047
    int r = rowBase + (q >> 5);
    int rr = (r < N) ? r : (N - 1);
    hs4[q] = in4[(size_t)rr * 32 + (q & 31)];
  }
  __syncthreads();

  float4 acc[8];
#pragma unroll
  for (int i = 0; i < 8; i++) acc[i] = make_float4(0.f, 0.f, 0.f, 0.f);

#pragma unroll 2
  for (int k = 0; k < 32; k++) {
    float4 w0 = W4[(k * 4 + 0) * 32 + c];
    float4 w1 = W4[(k * 4 + 1) * 32 + c];
    float4 w2 = W4[(k * 4 + 2) * 32 + c];
    float4 w3 = W4[(k * 4 + 3) * 32 + c];
#pragma unroll
    for (int i = 0; i < 8; i++) {
      float4 hv = hs4[(rg + 8 * i) * 32 + k];
      acc[i].x += hv.x * w0.x + hv.y * w1.x + hv.z * w2.x + hv.w * w3.x;
      acc[i].y += hv.x * w0.y + hv.y * w1.y + hv.z * w2.y + hv.w * w3.y;
      acc[i].z += hv.x * w0.z + hv.y * w1.z + hv.z * w2.z + hv.w * w3.z;
      acc[i].w += hv.x * w0.w + hv.y * w1.w + hv.z * w2.w + hv.w * w3.w;
    }
  }

  float4 bv = ((const float4*)bias)[c];
#pragma unroll
  for (int i = 0; i < 8; i++) {
    int row = rowBase + rg + 8 * i;
    if (row < N) {
      float4 o = make_float4(acc[i].x + bv.x, acc[i].y + bv.y,
                             acc[i].z + bv.z, acc[i].w + bv.w);
      if (RELU_OUT) {
        o.x = fmaxf(o.x, 0.f); o.y = fmaxf(o.y, 0.f);
        o.z = fmaxf(o.z, 0.f); o.w = fmaxf(o.w, 0.f);
      }
      ((float4*)out)[(size_t)row * 32 + c] = o;
    }
  }
}

// ============================ GCN gather-aggregate ============================
// Latency-bound (r9: VALUBusy 13%, VGPR 12): unroll x4 with independent
// accumulators -> 4 outstanding row loads per lane.
__global__ __launch_bounds__(256) void k_gcn_gather(
    const float* __restrict__ hw, const int* __restrict__ offs,
    const int2* __restrict__ pay, float* __restrict__ out, int N) {
  int n = blockIdx.x * 8 + (threadIdx.x >> 5);
  if (n >= N) return;
  int c = threadIdx.x & 31;
  int s = offs[n], t = offs[n + 1];
  const float4* hw4 = (const float4*)hw;
  float4 a0 = make_float4(0.f, 0.f, 0.f, 0.f);
  float4 a1 = make_float4(0.f, 0.f, 0.f, 0.f);
  float4 a2 = make_float4(0.f, 0.f, 0.f, 0.f);
  float4 a3 = make_float4(0.f, 0.f, 0.f, 0.f);
  int i = s;
  int t4 = s + ((t - s) & ~3);
  for (; i < t4; i += 4) {
    int2 p0 = pay[i], p1 = pay[i + 1], p2 = pay[i + 2], p3 = pay[i + 3];
    float4 h0 = hw4[(size_t)p0.x * 32 + c];
    float4 h1 = hw4[(size_t)p1.x * 32 + c];
    float4 h2 = hw4[(size_t)p2.x * 32 + c];
    float4 h3 = hw4[(size_t)p3.x * 32 + c];
    float v0 = __int_as_float(p0.y), v1 = __int_as_float(p1.y);
    float v2 = __int_as_float(p2.y), v3 = __int_as_float(p3.y);
    a0.x += v0 * h0.x; a0.y += v0 * h0.y; a0.z += v0 * h0.z; a0.w += v0 * h0.w;
    a1.x += v1 * h1.x; a1.y += v1 * h1.y; a1.z += v1 * h1.z; a1.w += v1 * h1.w;
    a2.x += v2 * h2.x; a2.y += v2 * h2.y; a2.z += v2 * h2.z; a2.w += v2 * h2.w;
    a3.x += v3 * h3.x; a3.y += v3 * h3.y; a3.z += v3 * h3.z; a3.w += v3 * h3.w;
  }
  for (; i < t; i++) {
    int2 p = pay[i];
    float v = __int_as_float(p.y);
    float4 hv = hw4[(size_t)p.x * 32 + c];
    a0.x += v * hv.x; a0.y += v * hv.y; a0.z += v * hv.z; a0.w += v * hv.w;
  }
  float4 o;
  o.x = fmaxf(a0.x + a1.x + a2.x + a3.x, 0.f);
  o.y = fmaxf(a0.y + a1.y + a2.y + a3.y, 0.f);
  o.z = fmaxf(a0.z + a1.z + a2.z + a3.z, 0.f);
  o.w = fmaxf(a0.w + a1.w + a2.w + a3.w, 0.f);
  ((float4*)(out + (size_t)n * H))[c] = o;
}

// ============================ pool + predictor ============================
__global__ __launch_bounds__(256) void k_gbounds(
    const int* __restrict__ batch, int* __restrict__ gstart, int N, int G) {
  int n = blockIdx.x * 256 + threadIdx.x;
  if (n > N) return;
  if (n == 0) {
    for (int g = 0; g <= batch[0]; g++) gstart[g] = 0;
  } else if (n == N) {
    for (int g = batch[N - 1] + 1; g <= G; g++) gstart[g] = N;
  } else {
    int b0 = batch[n - 1], b1 = batch[n];
    for (int g = b0 + 1; g <= b1; g++) gstart[g] = n;
  }
}

__global__ __launch_bounds__(128) void k_pool_seg(
    const float* __restrict__ h, const int* __restrict__ gstart,
    float* __restrict__ fp, int G) {
  int g = blockIdx.x;
  int j = threadIdx.x;
  int s = gstart[g], t = gstart[g + 1];
  float acc = 0.f;
  for (int n = s; n < t; n++) acc += h[(size_t)n * H + j];
  fp[(size_t)g * H + j] = acc;
}

__global__ __launch_bounds__(256) void k_pred2(
    const float* __restrict__ z, const float* __restrict__ Wp2,
    const float* __restrict__ bp2, float* __restrict__ out, int G) {
  int g = blockIdx.x * 4 + (threadIdx.x >> 6);
  if (g >= G) return;
  int l = threadIdx.x & 63;
  float2 zv = ((const float2*)z)[(size_t)g * 64 + l];
  float2 wv = ((const float2*)Wp2)[l];
  float v = zv.x * wv.x + zv.y * wv.y;
#pragma unroll
  for (int off = 32; off > 0; off >>= 1) v += __shfl_down(v, off, 64);
  if (l == 0) out[g] = v + bp2[0];
}

// ============================ launch ============================
extern "C" void kernel_launch(void* const* d_in, const int* in_sizes, int n_in,
                              void* d_out, int out_size, void* d_ws, size_t ws_size,
                              hipStream_t stream) {
  const float* node_attr  = (const float*)d_in[0];
  const float* edge_attr  = (const float*)d_in[1];
  const int*   edge_index = (const int*)d_in[2];
  const int*   adj_index  = (const int*)d_in[3];
  const float* adj_value  = (const float*)d_in[4];
  const int*   batch      = (const int*)d_in[5];
  const float* W_node  = (const float*)d_in[6];
  const float* W_edge  = (const float*)d_in[7];
  const float* b_embed = (const float*)d_in[8];
  const float* W1 = (const float*)d_in[9];
  const float* b1 = (const float*)d_in[10];
  const float* W2 = (const float*)d_in[11];
  const float* b2 = (const float*)d_in[12];
  const float* W3 = (const float*)d_in[13];
  const float* b3 = (const float*)d_in[14];
  const float* Wp1 = (const float*)d_in[15];
  const float* bp1 = (const float*)d_in[16];
  const float* Wp2 = (const float*)d_in[17];
  const float* bp2 = (const float*)d_in[18];
  float* out = (float*)d_out;

  const int E = in_sizes[4];           // 1,600,000
  const int N = in_sizes[5];           // 100,000
  const int G = out_size;              // 2048
  const int nbuk = (N + 63) >> 6;      // 1563
  const int p1b = (E + 8191) / 8192;

  // ---- workspace layout ----
  float* A     = (float*)d_ws;                       // N*H
  float* B     = A + (size_t)N * H;                  // N*H
  int2*  payF  = (int2*)(B + (size_t)N * H);         // E
  float* fpool = (float*)(payF + E);                 // G*H
  int*   bcnt1 = (int*)(fpool + (size_t)G * H);      // nbuk  } one memset
  int*   bcnt2 = bcnt1 + nbuk;                       // nbuk  }
  int*   bst1  = bcnt2 + nbuk;                       // nbuk+1
  int*   gcur1 = bst1 + nbuk + 1;                    // nbuk
  int*   bst2  = gcur1 + nbuk;                       // nbuk+1
  int*   gcur2 = bst2 + nbuk + 1;                    // nbuk
  int*   offs2 = gcur2 + nbuk;                       // N+1
  int*   gstart= offs2 + N + 1;                      // G+1
  // transient aliases (lifetimes by launch order):
  float* agg8  = A;                                  // N*FE; dead after embed_h
  int*   pkey  = (int*)B;                            // E ints; dead after embed_agg
  int2*  bpay2 = (int2*)(((int*)B) + E);             // E int2; dead after p2
  float* zbuf  = A;                                  // G*H; A free after last gather

  // ---- histograms + scans (both sorts) ----
  hipMemsetAsync(bcnt1, 0, (size_t)2 * nbuk * sizeof(int), stream);
  k_hist2<<<512, 256, 0, stream>>>(edge_index + E, adj_index, bcnt1, bcnt2, E, nbuk);
  k_scan<<<1, 1024, 0, stream>>>(bcnt1, bst1, gcur1, bcnt2, bst2, gcur2, nbuk);

  // ---- pass-1 scatters ----
  k_p1_scatter<1><<<p1b, 256, 0, stream>>>(edge_index + E, nullptr, nullptr,
                                           gcur1, pkey, nullptr, E, nbuk);
  k_p1_scatter<0><<<p1b, 256, 0, stream>>>(adj_index, adj_index + E, adj_value,
                                           gcur2, nullptr, bpay2, E, nbuk);

  // ---- embed agg + adj pass-2 ----
  k_embed_agg<<<nbuk, 256, 0, stream>>>(pkey, edge_attr, bst1, agg8, N);
  k_p2<<<nbuk, 256, 0, stream>>>(bpay2, bst2, offs2, payF, N, E);

  // ---- embed h -> B ----
  k_embed_h<<<4096, 256, 0, stream>>>(node_attr, W_node, W_edge, b_embed, agg8, B, N);

  k_gbounds<<<(N + 256) / 256, 256, 0, stream>>>(batch, gstart, N, G);

  // ---- 3 GCN layers: A = B@W+b ; B = relu(gather(A)) ----
  int gemm_blocks = (N + 63) / 64;
  int agb = (N + 7) / 8;
  k_gemm<0><<<gemm_blocks, 256, 0, stream>>>(B, W1, b1, A, N);
  k_gcn_gather<<<agb, 256, 0, stream>>>(A, offs2, payF, B, N);
  k_gemm<0><<<gemm_blocks, 256, 0, stream>>>(B, W2, b2, A, N);
  k_gcn_gather<<<agb, 256, 0, stream>>>(A, offs2, payF, B, N);
  k_gemm<0><<<gemm_blocks, 256, 0, stream>>>(B, W3, b3, A, N);
  k_gcn_gather<<<agb, 256, 0, stream>>>(A, offs2, payF, B, N);

  // ---- pool + predictor ----
  k_pool_seg<<<G, 128, 0, stream>>>(B, gstart, fpool, G);
  k_gemm<1><<<G / 64, 256, 0, stream>>>(fpool, Wp1, bp1, zbuf, G);
  k_pred2<<<(G + 3) / 4, 256, 0, stream>>>(zbuf, Wp2, bp2, out, G);
}

// Round 11
// 947.346 us; speedup vs baseline: 3.9695x; 1.0218x over previous
//
#include <hip/hip_runtime.h>

#define H 128
#define FN 16
#define FE 8
#define NBUK_MAX 1600   // buckets = ceil(N/64) = 1563 for N=100k

// ============================ histogram (both sorts fused) ============================
__global__ __launch_bounds__(256) void k_hist2(
    const int* __restrict__ k1, const int* __restrict__ k2,
    int* __restrict__ bcnt1, int* __restrict__ bcnt2, int E, int nbuk) {
  __shared__ int h1[NBUK_MAX], h2[NBUK_MAX];
  for (int i = threadIdx.x; i < nbuk; i += 256) { h1[i] = 0; h2[i] = 0; }
  __syncthreads();
  for (int e = blockIdx.x * 256 + threadIdx.x; e < E; e += gridDim.x * 256) {
    atomicAdd(&h1[k1[e] >> 6], 1);
    atomicAdd(&h2[k2[e] >> 6], 1);
  }
  __syncthreads();
  for (int i = threadIdx.x; i < nbuk; i += 256) {
    if (h1[i]) atomicAdd(&bcnt1[i], h1[i]);
    if (h2[i]) atomicAdd(&bcnt2[i], h2[i]);
  }
}

// ============================ single-block dual scan ============================
__global__ __launch_bounds__(1024) void k_scan(
    const int* __restrict__ cnt1, int* __restrict__ st1, int* __restrict__ gc1,
    const int* __restrict__ cnt2, int* __restrict__ st2, int* __restrict__ gc2,
    int nbuk) {
  __shared__ int s[1024];
  int tid = threadIdx.x;
  for (int pass = 0; pass < 2; pass++) {
    const int* cnt = pass ? cnt2 : cnt1;
    int* st = pass ? st2 : st1;
    int* gc = pass ? gc2 : gc1;
    int run = 0;
    for (int half = 0; half * 1024 < nbuk; half++) {
      int i = half * 1024 + tid;
      int v = (i < nbuk) ? cnt[i] : 0;
      s[tid] = v; __syncthreads();
      for (int off = 1; off < 1024; off <<= 1) {
        int t = (tid >= off) ? s[tid - off] : 0;
        __syncthreads();
        s[tid] += t;
        __syncthreads();
      }
      int excl = run + s[tid] - v;
      if (i < nbuk) { st[i] = excl; gc[i] = excl; }
      run += s[1023];
      __syncthreads();
    }
    if (tid == 0) st[nbuk] = run;
    __syncthreads();
  }
}

// ============================ pass-1 bucket scatter ============================
template <int PACKED>
__global__ __launch_bounds__(256) void k_p1_scatter(
    const int* __restrict__ key, const int* __restrict__ dsts,
    const float* __restrict__ vals, int* __restrict__ gcur,
    int* __restrict__ pkey, int2* __restrict__ bpay, int E, int nbuk) {
  __shared__ int hc[NBUK_MAX];
  int tid = threadIdx.x;
  int c0 = blockIdx.x * 8192;
  int c1 = min(c0 + 8192, E);
  for (int i = tid; i < nbuk; i += 256) hc[i] = 0;
  __syncthreads();
  for (int e = c0 + tid; e < c1; e += 256)
    atomicAdd(&hc[key[e] >> 6], 1);
  __syncthreads();
  for (int i = tid; i < nbuk; i += 256) {
    int c = hc[i];
    if (c) hc[i] = atomicAdd(&gcur[i], c);
  }
  __syncthreads();
  for (int e = c0 + tid; e < c1; e += 256) {
    int k = key[e];
    int pos = atomicAdd(&hc[k >> 6], 1);
    if (PACKED) {
      pkey[pos] = (e << 6) | (k & 63);
    } else {
      bpay[pos] = make_int2(dsts[e] | ((k & 63) << 20), __float_as_int(vals[e]));
    }
  }
}

// ============================ embed bucket-sum ============================
__global__ __launch_bounds__(256) void k_embed_agg(
    const int* __restrict__ pkey, const float* __restrict__ edge_attr,
    const int* __restrict__ bstart, float* __restrict__ agg8, int N) {
  __shared__ float lds[FE][64];
  int b = blockIdx.x, tid = threadIdx.x;
  for (int i = tid; i < FE * 64; i += 256) ((float*)lds)[i] = 0.f;
  __syncthreads();
  int s = bstart[b], t = bstart[b + 1];
  int i = s + tid;
  for (; i + 256 < t; i += 512) {
    int pk0 = pkey[i], pk1 = pkey[i + 256];
    const float4* e0 = (const float4*)(edge_attr + (size_t)(pk0 >> 6) * FE);
    const float4* e1 = (const float4*)(edge_attr + (size_t)(pk1 >> 6) * FE);
    float4 a0 = e0[0], b0 = e0[1], a1 = e1[0], b1 = e1[1];
    int s0 = pk0 & 63, s1 = pk1 & 63;
    atomicAdd(&lds[0][s0], a0.x);  atomicAdd(&lds[1][s0], a0.y);
    atomicAdd(&lds[2][s0], a0.z);  atomicAdd(&lds[3][s0], a0.w);
    atomicAdd(&lds[4][s0], b0.x);  atomicAdd(&lds[5][s0], b0.y);
    atomicAdd(&lds[6][s0], b0.z);  atomicAdd(&lds[7][s0], b0.w);
    atomicAdd(&lds[0][s1], a1.x);  atomicAdd(&lds[1][s1], a1.y);
    atomicAdd(&lds[2][s1], a1.z);  atomicAdd(&lds[3][s1], a1.w);
    atomicAdd(&lds[4][s1], b1.x);  atomicAdd(&lds[5][s1], b1.y);
    atomicAdd(&lds[6][s1], b1.z);  atomicAdd(&lds[7][s1], b1.w);
  }
  for (; i < t; i += 256) {
    int pk = pkey[i];
    int e = pk >> 6, slot = pk & 63;
    const float4* ea = (const float4*)(edge_attr + (size_t)e * FE);
    float4 a = ea[0], b4 = ea[1];
    atomicAdd(&lds[0][slot], a.x);  atomicAdd(&lds[1][slot], a.y);
    atomicAdd(&lds[2][slot], a.z);  atomicAdd(&lds[3][slot], a.w);
    atomicAdd(&lds[4][slot], b4.x); atomicAdd(&lds[5][slot], b4.y);
    atomicAdd(&lds[6][slot], b4.z); atomicAdd(&lds[7][slot], b4.w);
  }
  __syncthreads();
  int node0 = b * 64;
  for (int j = tid; j < 64 * FE; j += 256) {
    int n = node0 + (j >> 3);
    if (n < N) agg8[(size_t)n * FE + (j & 7)] = lds[j & 7][j >> 3];
  }
}

// ============================ pass-2 for adj sort (also emits rs = rowsum(val)) ============================
__global__ __launch_bounds__(256) void k_p2(
    const int2* __restrict__ bpay, const int* __restrict__ bstart,
    int* __restrict__ offs, int2* __restrict__ payF, float* __restrict__ rs,
    int N, int E) {
  __shared__ int cnt[64], scn[64], cur[64];
  __shared__ float vsum[64];
  int b = blockIdx.x, tid = threadIdx.x;
  int s = bstart[b], t = bstart[b + 1];
  if (tid < 64) { cnt[tid] = 0; vsum[tid] = 0.f; }
  __syncthreads();
  for (int i = s + tid; i < t; i += 256) atomicAdd(&cnt[(bpay[i].x >> 20) & 63], 1);
  __syncthreads();
  if (tid < 64) scn[tid] = cnt[tid];
  __syncthreads();
  for (int off = 1; off < 64; off <<= 1) {
    int v = 0;
    if (tid < 64 && tid >= off) v = scn[tid - off];
    __syncthreads();
    if (tid < 64 && tid >= off) scn[tid] += v;
    __syncthreads();
  }
  if (tid < 64) {
    int excl = s + scn[tid] - cnt[tid];
    cur[tid] = excl;
    int node = b * 64 + tid;
    if (node < N) offs[node] = excl;
  }
  if (b == 0 && tid == 0) offs[N] = E;
  __syncthreads();
  for (int i = s + tid; i < t; i += 256) {
    int2 p = bpay[i];
    int slot = (p.x >> 20) & 63;
    int pos = atomicAdd(&cur[slot], 1);
    payF[pos] = make_int2(p.x & 0xFFFFF, p.y);
    atomicAdd(&vsum[slot], __int_as_float(p.y));
  }
  __syncthreads();
  if (tid < 64) {
    int node = b * 64 + tid;
    if (node < N) rs[node] = vsum[tid];
  }
}

// ============================ embed h ============================
__global__ __launch_bounds__(256) void k_embed_h(
    const float* __restrict__ node_attr, const float* __restrict__ Wn,
    const float* __restrict__ We8, const float* __restrict__ b,
    const float* __restrict__ agg8, float* __restrict__ h, int N) {
  __shared__ float Ws[FN * H];
  __shared__ float Es[FE * H];
  __shared__ float na[2][FN];
  __shared__ float a8[2][FE];
  for (int i = threadIdx.x; i < FN * H; i += 256) Ws[i] = Wn[i];
  for (int i = threadIdx.x; i < FE * H; i += 256) Es[i] = We8[i];
  int lane = threadIdx.x & 127;
  int sub  = threadIdx.x >> 7;
  for (int n0 = blockIdx.x * 2; n0 < N; n0 += gridDim.x * 2) {
    int n = n0 + sub;
    __syncthreads();
    if (n < N) {
      if (lane < FN) na[sub][lane] = node_attr[(size_t)n * FN + lane];
      else if (lane < FN + FE) a8[sub][lane - FN] = agg8[(size_t)n * FE + (lane - FN)];
    }
    __syncthreads();
    if (n < N) {
      float acc = b[lane];
#pragma unroll
      for (int k = 0; k < FN; k++) acc += na[sub][k] * Ws[k * H + lane];
#pragma unroll
      for (int k = 0; k < FE; k++) acc += a8[sub][k] * Es[k * H + lane];
      h[(size_t)n * H + lane] = fmaxf(acc, 0.f);
    }
  }
}

// ============================ fused GCN layer ============================
// out[n] = relu( (sum val*h[dst]) @ W + rs[n]*b )  — gather lands directly in
// the single-sync GEMM's LDS tile; cross-block overlap (5 blocks/CU @ 32 KB)
// hides the latency-bound gather behind other blocks' GEMM phase.
__global__ __launch_bounds__(256) void k_fused(
    const float* __restrict__ h, const int* __restrict__ offs,
    const int2* __restrict__ pay, const float* __restrict__ W,
    const float* __restrict__ bias, const float* __restrict__ rs,
    float* __restrict__ out, int N) {
  __shared__ float4 hs4[64 * 32];   // 32 KB: [row][k4]
  int tid = threadIdx.x;
  int c  = tid & 31;
  int rg = tid >> 5;
  int base = blockIdx.x * 64;
  const float4* h4 = (const float4*)h;

  // ---- phase 1: group rg aggregates rows rg*8 .. rg*8+7 ----
  for (int r = 0; r < 8; r++) {
    int row = rg * 8 + r;
    int n = base + row;
    float4 a0 = make_float4(0.f, 0.f, 0.f, 0.f);
    float4 a1 = make_float4(0.f, 0.f, 0.f, 0.f);
    float4 a2 = make_float4(0.f, 0.f, 0.f, 0.f);
    float4 a3 = make_float4(0.f, 0.f, 0.f, 0.f);
    if (n < N) {
      int s = offs[n], t = offs[n + 1];
      int i = s, t4 = s + ((t - s) & ~3);
      for (; i < t4; i += 4) {
        int2 p0 = pay[i], p1 = pay[i + 1], p2 = pay[i + 2], p3 = pay[i + 3];
        float4 h0 = h4[(size_t)p0.x * 32 + c];
        float4 h1 = h4[(size_t)p1.x * 32 + c];
        float4 h2 = h4[(size_t)p2.x * 32 + c];
        float4 h3 = h4[(size_t)p3.x * 32 + c];
        float v0 = __int_as_float(p0.y), v1 = __int_as_float(p1.y);
        float v2 = __int_as_float(p2.y), v3 = __int_as_float(p3.y);
        a0.x += v0 * h0.x; a0.y += v0 * h0.y; a0.z += v0 * h0.z; a0.w += v0 * h0.w;
        a1.x += v1 * h1.x; a1.y += v1 * h1.y; a1.z += v1 * h1.z; a1.w += v1 * h1.w;
        a2.x += v2 * h2.x; a2.y += v2 * h2.y; a2.z += v2 * h2.z; a2.w += v2 * h2.w;
        a3.x += v3 * h3.x; a3.y += v3 * h3.y; a3.z += v3 * h3.z; a3.w += v3 * h3.w;
      }
      for (; i < t; i++) {
        int2 p = pay[i];
        float v = __int_as_float(p.y);
        float4 hv = h4[(size_t)p.x * 32 + c];
        a0.x += v * hv.x; a0.y += v * hv.y; a0.z += v * hv.z; a0.w += v * hv.w;
      }
    }
    hs4[row * 32 + c] = make_float4(a0.x + a1.x + a2.x + a3.x,
                                    a0.y + a1.y + a2.y + a3.y,
                                    a0.z + a1.z + a2.z + a3.z,
                                    a0.w + a1.w + a2.w + a3.w);
  }
  __syncthreads();

  // ---- phase 2: GEMM from LDS; W coalesced from global (L1/L2-hot) ----
  const float4* W4 = (const float4*)W;   // [128][32]
  float4 acc[8];
#pragma unroll
  for (int i = 0; i < 8; i++) acc[i] = make_float4(0.f, 0.f, 0.f, 0.f);
#pragma unroll 2
  for (int k = 0; k < 32; k++) {
    float4 w0 = W4[(k * 4 + 0) * 32 + c];
    float4 w1 = W4[(k * 4 + 1) * 32 + c];
    float4 w2 = W4[(k * 4 + 2) * 32 + c];
    float4 w3 = W4[(k * 4 + 3) * 32 + c];
#pragma unroll
    for (int i = 0; i < 8; i++) {
      float4 hv = hs4[(rg + 8 * i) * 32 + k];   // wave-uniform broadcast
      acc[i].x += hv.x * w0.x + hv.y * w1.x + hv.z * w2.x + hv.w * w3.x;
      acc[i].y += hv.x * w0.y + hv.y * w1.y + hv.z * w2.y + hv.w * w3.y;
      acc[i].z += hv.x * w0.z + hv.y * w1.z + hv.z * w2.z + hv.w * w3.z;
      acc[i].w += hv.x * w0.w + hv.y * w1.w + hv.z * w2.w + hv.w * w3.w;
    }
  }

  float4 bv = ((const float4*)bias)[c];
#pragma unroll
  for (int i = 0; i < 8; i++) {
    int row = rg + 8 * i;
    int n = base + row;
    if (n < N) {
      float rsv = rs[n];
      float4 o;
      o.x = fmaxf(acc[i].x + rsv * bv.x, 0.f);
      o.y = fmaxf(acc[i].y + rsv * bv.y, 0.f);
      o.z = fmaxf(acc[i].z + rsv * bv.z, 0.f);
      o.w = fmaxf(acc[i].w + rsv * bv.w, 0.f);
      ((float4*)out)[(size_t)n * 32 + c] = o;
    }
  }
}

// ============================ plain GEMM (predictor) ============================
template <int RELU_OUT>
__global__ __launch_bounds__(256) void k_gemm(
    const float* __restrict__ in, const float* __restrict__ W,
    const float* __restrict__ bias, float* __restrict__ out, int N) {
  __shared__ float4 hs4[64 * 32];
  int tid = threadIdx.x;
  int c  = tid & 31;
  int rg = tid >> 5;
  int rowBase = blockIdx.x * 64;
  const float4* in4 = (const float4*)in;
  const float4* W4  = (const float4*)W;
#pragma unroll
  for (int j = 0; j < 8; j++) {
    int q = tid + 256 * j;
    int r = rowBase + (q >> 5);
    int rr = (r < N) ? r : (N - 1);
    hs4[q] = in4[(size_t)rr * 32 + (q & 31)];
  }
  __syncthreads();
  float4 acc[8];
#pragma unroll
  for (int i = 0; i < 8; i++) acc[i] = make_float4(0.f, 0.f, 0.f, 0.f);
#pragma unroll 2
  for (int k = 0; k < 32; k++) {
    float4 w0 = W4[(k * 4 + 0) * 32 + c];
    float4 w1 = W4[(k * 4 + 1) * 32 + c];
    float4 w2 = W4[(k * 4 + 2) * 32 + c];
    float4 w3 = W4[(k * 4 + 3) * 32 + c];
#pragma unroll
    for (int i = 0; i < 8; i++) {
      float4 hv = hs4[(rg + 8 * i) * 32 + k];
      acc[i].x += hv.x * w0.x + hv.y * w1.x + hv.z * w2.x + hv.w * w3.x;
      acc[i].y += hv.x * w0.y + hv.y * w1.y + hv.z * w2.y + hv.w * w3.y;
      acc[i].z += hv.x * w0.z + hv.y * w1.z + hv.z * w2.z + hv.w * w3.z;
      acc[i].w += hv.x * w0.w + hv.y * w1.w + hv.z * w2.w + hv.w * w3.w;
    }
  }
  float4 bv = ((const float4*)bias)[c];
#pragma unroll
  for (int i = 0; i < 8; i++) {
    int row = rowBase + rg + 8 * i;
    if (row < N) {
      float4 o = make_float4(acc[i].x + bv.x, acc[i].y + bv.y,
                             acc[i].z + bv.z, acc[i].w + bv.w);
      if (RELU_OUT) {
        o.x = fmaxf(o.x, 0.f); o.y = fmaxf(o.y, 0.f);
        o.z = fmaxf(o.z, 0.f); o.w = fmaxf(o.w, 0.f);
      }
      ((float4*)out)[(size_t)row * 32 + c] = o;
    }
  }
}

// ============================ pool + predictor ============================
__global__ __launch_bounds__(256) void k_gbounds(
    const int* __restrict__ batch, int* __restrict__ gstart, int N, int G) {
  int n = blockIdx.x * 256 + threadIdx.x;
  if (n > N) return;
  if (n == 0) {
    for (int g = 0; g <= batch[0]; g++) gstart[g] = 0;
  } else if (n == N) {
    for (int g = batch[N - 1] + 1; g <= G; g++) gstart[g] = N;
  } else {
    int b0 = batch[n - 1], b1 = batch[n];
    for (int g = b0 + 1; g <= b1; g++) gstart[g] = n;
  }
}

__global__ __launch_bounds__(128) void k_pool_seg(
    const float* __restrict__ h, const int* __restrict__ gstart,
    float* __restrict__ fp, int G) {
  int g = blockIdx.x;
  int j = threadIdx.x;
  int s = gstart[g], t = gstart[g + 1];
  float acc = 0.f;
  for (int n = s; n < t; n++) acc += h[(size_t)n * H + j];
  fp[(size_t)g * H + j] = acc;
}

__global__ __launch_bounds__(256) void k_pred2(
    const float* __restrict__ z, const float* __restrict__ Wp2,
    const float* __restrict__ bp2, float* __restrict__ out, int G) {
  int g = blockIdx.x * 4 + (threadIdx.x >> 6);
  if (g >= G) return;
  int l = threadIdx.x & 63;
  float2 zv = ((const float2*)z)[(size_t)g * 64 + l];
  float2 wv = ((const float2*)Wp2)[l];
  float v = zv.x * wv.x + zv.y * wv.y;
#pragma unroll
  for (int off = 32; off > 0; off >>= 1) v += __shfl_down(v, off, 64);
  if (l == 0) out[g] = v + bp2[0];
}

// ============================ launch ============================
extern "C" void kernel_launch(void* const* d_in, const int* in_sizes, int n_in,
                              void* d_out, int out_size, void* d_ws, size_t ws_size,
                              hipStream_t stream) {
  const float* node_attr  = (const float*)d_in[0];
  const float* edge_attr  = (const float*)d_in[1];
  const int*   edge_index = (const int*)d_in[2];
  const int*   adj_index  = (const int*)d_in[3];
  const float* adj_value  = (const float*)d_in[4];
  const int*   batch      = (const int*)d_in[5];
  const float* W_node  = (const float*)d_in[6];
  const float* W_edge  = (const float*)d_in[7];
  const float* b_embed = (const float*)d_in[8];
  const float* W1 = (const float*)d_in[9];
  const float* b1 = (const float*)d_in[10];
  const float* W2 = (const float*)d_in[11];
  const float* b2 = (const float*)d_in[12];
  const float* W3 = (const float*)d_in[13];
  const float* b3 = (const float*)d_in[14];
  const float* Wp1 = (const float*)d_in[15];
  const float* bp1 = (const float*)d_in[16];
  const float* Wp2 = (const float*)d_in[17];
  const float* bp2 = (const float*)d_in[18];
  float* out = (float*)d_out;

  const int E = in_sizes[4];           // 1,600,000
  const int N = in_sizes[5];           // 100,000
  const int G = out_size;              // 2048
  const int nbuk = (N + 63) >> 6;      // 1563
  const int p1b = (E + 8191) / 8192;

  // ---- workspace layout ----
  float* A     = (float*)d_ws;                       // N*H
  float* B     = A + (size_t)N * H;                  // N*H
  int2*  payF  = (int2*)(B + (size_t)N * H);         // E
  float* fpool = (float*)(payF + E);                 // G*H
  int*   bcnt1 = (int*)(fpool + (size_t)G * H);      // nbuk  } one memset
  int*   bcnt2 = bcnt1 + nbuk;                       // nbuk  }
  int*   bst1  = bcnt2 + nbuk;                       // nbuk+1
  int*   gcur1 = bst1 + nbuk + 1;                    // nbuk
  int*   bst2  = gcur1 + nbuk;                       // nbuk+1
  int*   gcur2 = bst2 + nbuk + 1;                    // nbuk
  int*   offs2 = gcur2 + nbuk;                       // N+1
  int*   gstart= offs2 + N + 1;                      // G+1
  float* rs    = (float*)(gstart + G + 1);           // N
  // transient aliases (lifetimes by launch order):
  float* agg8  = A;                                  // N*FE; dead after embed_h
  int*   pkey  = (int*)B;                            // E ints; dead after embed_agg
  int2*  bpay2 = (int2*)(((int*)B) + E);             // E int2; dead after p2
  float* zbuf  = B;                                  // G*H; B free after layer-3 reads it

  // ---- histograms + scans (both sorts) ----
  hipMemsetAsync(bcnt1, 0, (size_t)2 * nbuk * sizeof(int), stream);
  k_hist2<<<512, 256, 0, stream>>>(edge_index + E, adj_index, bcnt1, bcnt2, E, nbuk);
  k_scan<<<1, 1024, 0, stream>>>(bcnt1, bst1, gcur1, bcnt2, bst2, gcur2, nbuk);

  // ---- pass-1 scatters ----
  k_p1_scatter<1><<<p1b, 256, 0, stream>>>(edge_index + E, nullptr, nullptr,
                                           gcur1, pkey, nullptr, E, nbuk);
  k_p1_scatter<0><<<p1b, 256, 0, stream>>>(adj_index, adj_index + E, adj_value,
                                           gcur2, nullptr, bpay2, E, nbuk);

  // ---- embed agg + adj pass-2 (emits rs) ----
  k_embed_agg<<<nbuk, 256, 0, stream>>>(pkey, edge_attr, bst1, agg8, N);
  k_p2<<<nbuk, 256, 0, stream>>>(bpay2, bst2, offs2, payF, rs, N, E);

  // ---- embed h -> B ----
  k_embed_h<<<4096, 256, 0, stream>>>(node_attr, W_node, W_edge, b_embed, agg8, B, N);

  k_gbounds<<<(N + 256) / 256, 256, 0, stream>>>(batch, gstart, N, G);

  // ---- 3 fused GCN layers: out = relu(gather(in)@W + rs*b) ----
  int lb = (N + 63) / 64;
  k_fused<<<lb, 256, 0, stream>>>(B, offs2, payF, W1, b1, rs, A, N);
  k_fused<<<lb, 256, 0, stream>>>(A, offs2, payF, W2, b2, rs, B, N);
  k_fused<<<lb, 256, 0, stream>>>(B, offs2, payF, W3, b3, rs, A, N);

  // ---- pool + predictor ----
  k_pool_seg<<<G, 128, 0, stream>>>(A, gstart, fpool, G);
  k_gemm<1><<<(G + 63) / 64, 256, 0, stream>>>(fpool, Wp1, bp1, zbuf, G);
  k_pred2<<<(G + 3) / 4, 256, 0, stream>>>(zbuf, Wp2, bp2, out, G);
}